// Round 20
// baseline (2275.368 us; speedup 1.0000x reference)
//
#include <hip/hip_runtime.h>
#include <hip/hip_bf16.h>
#include <math.h>

#define D 768
#define NH 12
#define HD 64
#define NEXP 4
#define FF 3072
#define NBLK 2
#define DEPTH 6
#define NA 64
#define NB 32
#define NC 192
#define BATCH 8
#define TTRAJ 256
#define NTOK 544
#define MAXTOK 1536
#define MOER 2304

typedef __attribute__((ext_vector_type(8))) short short8v;
typedef __attribute__((ext_vector_type(4))) float f32x4;

__device__ __forceinline__ float siluf(float v) { return v / (1.f + expf(-v)); }
__device__ __forceinline__ float geluf(float v) {
    float u = 0.7978845608028654f * (v + 0.044715f * v * v * v);
    return 0.5f * v * (1.f + tanhf(u));
}
__device__ __forceinline__ unsigned short f2bf(float f) {
    union { float f; unsigned u; } v; v.f = f;
    unsigned r = v.u + 0x7fffu + ((v.u >> 16) & 1u);
    return (unsigned short)(r >> 16);
}
__device__ __forceinline__ float bf2f(unsigned short u) {
    union { unsigned u; float f; } v; v.u = ((unsigned)u) << 16; return v.f;
}
__device__ __forceinline__ void gl16(const unsigned short* g, unsigned short* l) {
    __builtin_amdgcn_global_load_lds(
        (const __attribute__((address_space(1))) void*)g,
        (__attribute__((address_space(3))) void*)l, 16, 0, 0);
}

// ---------------- timestep embedding ----------------
__global__ void timestep_kernel(const int* __restrict__ t, unsigned short* __restrict__ tembP) {
    int i = blockIdx.x * blockDim.x + threadIdx.x;
    if (i >= 128 * 256) return;
    int b = i >> 8, j = i & 255;
    float v = 0.f;
    if (b < BATCH) {
        int jj = (j & 127);
        float freq = expf(-logf(10000.f) * (float)jj / 128.f);
        float ang = (float)t[b] * freq;
        v = (j < 128) ? cosf(ang) : sinf(ang);
    }
    tembP[i] = f2bf(v);
}

__global__ void add_ftime(float* __restrict__ traj, const float* __restrict__ wf, int total) {
    int i = blockIdx.x * blockDim.x + threadIdx.x;
    if (i >= total) return;
    int col = i % D;
    int n = (i / D) % TTRAJ;
    traj[i] += wf[(n & 7) * D + col];
}

__global__ void cvt_bf16(const float* __restrict__ in, unsigned short* __restrict__ out, int n8) {
    int i = blockIdx.x * blockDim.x + threadIdx.x;
    if (i >= n8) return;
    float4 a = *(const float4*)(in + i * 8);
    float4 b = *(const float4*)(in + i * 8 + 4);
    unsigned short t[8] = {f2bf(a.x), f2bf(a.y), f2bf(a.z), f2bf(a.w),
                           f2bf(b.x), f2bf(b.y), f2bf(b.z), f2bf(b.w)};
    *(short8v*)(out + i * 8) = *(short8v*)t;
}

__global__ void zero_f32(float* __restrict__ p, int n4) {
    int i = blockIdx.x * blockDim.x + threadIdx.x;
    if (i < n4) *(float4*)(p + (size_t)i * 4) = make_float4(0.f, 0.f, 0.f, 0.f);
}

// finalize split-K MoE phase2: abf += gval * scratch
__global__ void moe_fin(const float* __restrict__ scr, const float* __restrict__ gval,
                        unsigned short* __restrict__ abf, int total4) {
    int i = blockIdx.x * blockDim.x + threadIdx.x;
    if (i >= total4) return;
    size_t base = (size_t)i * 4;
    int tok = (int)(base / 768);
    float g = gval[tok];
    float4 s = *(const float4*)(scr + base);
    unsigned short* p = abf + base;
    p[0] = f2bf(bf2f(p[0]) + g * s.x);
    p[1] = f2bf(bf2f(p[1]) + g * s.y);
    p[2] = f2bf(bf2f(p[2]) + g * s.z);
    p[3] = f2bf(bf2f(p[3]) + g * s.w);
}

// ---------------- small f32 GEMM (traj embed, K=7) ----------------
template<int ACT>
__global__ __launch_bounds__(256) void gemm_act(
    const float* __restrict__ A, int lda,
    const float* __restrict__ B, int ldb,
    const float* __restrict__ bias,
    float* __restrict__ C, int ldc,
    int M, int N, int K)
{
    __shared__ float As[16][65];
    __shared__ float Bs[16][65];
    int tid = threadIdx.x;
    int tx = tid & 15, ty = tid >> 4;
    int row0 = blockIdx.y * 64, col0 = blockIdx.x * 64;
    float acc[4][4] = {};
    for (int k0 = 0; k0 < K; k0 += 16) {
        #pragma unroll
        for (int i = 0; i < 4; ++i) {
            int e = tid + 256 * i; int m = e >> 4; int kk = e & 15;
            int gr = row0 + m, gk = k0 + kk;
            As[kk][m] = (gr < M && gk < K) ? A[(size_t)gr * lda + gk] : 0.f;
        }
        #pragma unroll
        for (int i = 0; i < 4; ++i) {
            int e = tid + 256 * i; int kk = e >> 6; int n = e & 63;
            int gk = k0 + kk, gc = col0 + n;
            Bs[kk][n] = (gk < K && gc < N) ? B[(size_t)gk * ldb + gc] : 0.f;
        }
        __syncthreads();
        #pragma unroll
        for (int kk = 0; kk < 16; ++kk) {
            float a[4], bv[4];
            #pragma unroll
            for (int i = 0; i < 4; ++i) a[i] = As[kk][ty * 4 + i];
            #pragma unroll
            for (int j = 0; j < 4; ++j) bv[j] = Bs[kk][tx * 4 + j];
            #pragma unroll
            for (int i = 0; i < 4; ++i)
                #pragma unroll
                for (int j = 0; j < 4; ++j) acc[i][j] += a[i] * bv[j];
        }
        __syncthreads();
    }
    #pragma unroll
    for (int i = 0; i < 4; ++i) {
        int gr = row0 + ty * 4 + i; if (gr >= M) continue;
        #pragma unroll
        for (int j = 0; j < 4; ++j) {
            int gc = col0 + tx * 4 + j; if (gc >= N) continue;
            float v = acc[i][j] + (bias ? bias[gc] : 0.f);
            if (ACT == 1) v = siluf(v);
            if (ACT == 2) v = geluf(v);
            C[(size_t)gr * ldc + gc] = v;
        }
    }
}

// ---------------- weight transpose + cvt ----------------
__global__ __launch_bounds__(256) void transpose_cvt(
    const float* __restrict__ in, unsigned short* __restrict__ out, int K, int N)
{
    __shared__ unsigned short Ls[64][72];
    const float* src = in + (size_t)blockIdx.z * K * N;
    unsigned short* dst = out + (size_t)blockIdx.z * K * N;
    int k0 = blockIdx.y * 64, n0 = blockIdx.x * 64;
    int tid = threadIdx.x;
    int r = tid >> 2, c0 = (tid & 3) * 16;
    {
        const float* sp = src + (size_t)(k0 + r) * N + n0 + c0;
        #pragma unroll
        for (int j = 0; j < 16; j += 4) {
            float4 f = *(const float4*)(sp + j);
            Ls[c0 + j + 0][r] = f2bf(f.x);
            Ls[c0 + j + 1][r] = f2bf(f.y);
            Ls[c0 + j + 2][r] = f2bf(f.z);
            Ls[c0 + j + 3][r] = f2bf(f.w);
        }
    }
    __syncthreads();
    {
        unsigned short tmp[16];
        #pragma unroll
        for (int j = 0; j < 16; ++j) tmp[j] = Ls[r][c0 + j];
        unsigned short* dp = dst + (size_t)(n0 + r) * K + k0 + c0;
        *(short8v*)dp = *(short8v*)tmp;
        *(short8v*)(dp + 8) = *(short8v*)(tmp + 8);
    }
}

// ---------------- MFMA GEMM: BK=32, dbuf, TM=128/64, TN=128/64, 4 waves ----
// OUT: 0 f32, 1 bf16 (+qscale), 2 bf16 gated residual (read-modify-write Cb).
template<int ACT, int OUT, int TN, int TM>
__global__ __launch_bounds__(256) void gemm_lds(
    const unsigned short* __restrict__ A,
    const unsigned short* __restrict__ BT,
    const float* __restrict__ bias,
    float* __restrict__ Cf, unsigned short* __restrict__ Cb, int ldc,
    int K, int qscale_cols,
    const float* __restrict__ mod, int modstride, int gchunk, int ntok, int mrows,
    size_t bt_zs = 0, size_t bias_zs = 0, size_t c_zs = 0)
{
    constexpr int NCF = TN / 32;       // col frags per wave
    constexpr int NBS = TN / 64;       // B stage issues per thread
    constexpr int NMR = TM / 32;       // row frags per wave
    constexpr int NAI = TM / 64;       // A stage issues per thread
    constexpr int NST = (NAI > NBS) ? NAI : NBS;   // staging addr table size
    if (bt_zs) BT += (size_t)blockIdx.z * bt_zs;
    if (bias && bias_zs) bias += (size_t)blockIdx.z * bias_zs;
    if (c_zs) { if (Cf) Cf += (size_t)blockIdx.z * c_zs; if (Cb) Cb += (size_t)blockIdx.z * c_zs; }
    __shared__ unsigned short As[2][TM * 32];
    __shared__ unsigned short Bs[2][TN * 32];
    int tid = threadIdx.x, w = tid >> 6, lane = tid & 63;
    int row0 = blockIdx.y * TM, col0 = blockIdx.x * TN;
    int wrow = (w >> 1) * (TM / 2), wcol = (w & 1) * (TN / 2);
    int lr = lane & 15, g = lane >> 4;
    f32x4 acc[NMR][NCF] = {};

    int ra[NST], ka[NST], la[NST];
    #pragma unroll
    for (int i = 0; i < NST; ++i) {
        int off = tid * 16 + i * 4096;
        int row = off >> 6;
        int slot = (off >> 4) & 3;
        ra[i] = row;
        ka[i] = (slot ^ ((row >> 1) & 3)) * 8;
        la[i] = off >> 1;
    }
    int nt = K >> 5, cur = 0;
    #pragma unroll
    for (int i = 0; i < NAI; ++i)
        gl16(A + (size_t)(row0 + ra[i]) * K + ka[i], &As[0][la[i]]);
    #pragma unroll
    for (int i = 0; i < NBS; ++i)
        gl16(BT + (size_t)(col0 + ra[i]) * K + ka[i], &Bs[0][la[i]]);

    for (int t = 0; t < nt; ++t) {
        __syncthreads();
        if (t + 1 < nt) {
            int k0 = (t + 1) << 5;
            #pragma unroll
            for (int i = 0; i < NAI; ++i)
                gl16(A + (size_t)(row0 + ra[i]) * K + k0 + ka[i], &As[cur ^ 1][la[i]]);
            #pragma unroll
            for (int i = 0; i < NBS; ++i)
                gl16(BT + (size_t)(col0 + ra[i]) * K + k0 + ka[i], &Bs[cur ^ 1][la[i]]);
        }
        short8v av[NMR], bv[NCF];
        #pragma unroll
        for (int mr = 0; mr < NMR; ++mr) {
            int row = wrow + mr * 16 + lr;
            av[mr] = *(const short8v*)&As[cur][row * 32 + (g ^ ((row >> 1) & 3)) * 8];
        }
        #pragma unroll
        for (int nc = 0; nc < NCF; ++nc) {
            int row = wcol + nc * 16 + lr;
            bv[nc] = *(const short8v*)&Bs[cur][row * 32 + (g ^ ((row >> 1) & 3)) * 8];
        }
        #pragma unroll
        for (int mr = 0; mr < NMR; ++mr)
            #pragma unroll
            for (int nc = 0; nc < NCF; ++nc)
                acc[mr][nc] = __builtin_amdgcn_mfma_f32_16x16x32_bf16(
                    av[mr], bv[nc], acc[mr][nc], 0, 0, 0);
        cur ^= 1;
    }
    int rbase = g * 4;
    #pragma unroll
    for (int mr = 0; mr < NMR; ++mr) {
        #pragma unroll
        for (int nc = 0; nc < NCF; ++nc) {
            int gc = col0 + wcol + nc * 16 + lr;
            float bb = bias ? bias[gc] : 0.f;
            #pragma unroll
            for (int r = 0; r < 4; ++r) {
                int gr = row0 + wrow + mr * 16 + rbase + r;
                if (gr >= mrows) continue;
                float v = acc[mr][nc][r] + bb;
                if (ACT == 1) v = siluf(v);
                if (ACT == 2) v = geluf(v);
                if (OUT == 0) {
                    Cf[(size_t)gr * ldc + gc] = v;
                } else if (OUT == 1) {
                    if (gc < qscale_cols) v *= 0.125f;
                    Cb[(size_t)gr * ldc + gc] = f2bf(v);
                } else {
                    float gg = 1.f;
                    if (mod) gg = mod[(size_t)(gr / ntok) * modstride + gchunk * D + gc];
                    size_t idx = (size_t)gr * ldc + gc;
                    Cb[idx] = f2bf(bf2f(Cb[idx]) + gg * v);
                }
            }
        }
    }
}

// ---------------- MoE gathered MFMA GEMM ----------
template<int PHASE>
__global__ __launch_bounds__(256) void moe_lds(
    const unsigned short* __restrict__ A,
    const unsigned short* __restrict__ BTconv,
    unsigned short* __restrict__ Cb,
    const int* __restrict__ cnt, const int* __restrict__ list,
    const float* __restrict__ gval, int RT, int egbase)
{
    constexpr int K  = (PHASE == 1) ? 768 : 3072;
    constexpr int TN = (PHASE == 1) ? 128 : 64;
    constexpr int NCF = TN / 32;
    constexpr int NBS = TN / 64;
    int egl = blockIdx.y / RT, rt = blockIdx.y % RT;
    int eg = egbase + egl;
    int c0 = cnt[eg];
    int mbase = rt * 128;
    if (mbase >= c0) return;
    int mcount = min(128, c0 - mbase);
    __shared__ int toks[128];
    int tid = threadIdx.x, w = tid >> 6, lane = tid & 63;
    if (tid < 128) toks[tid] = list[eg * MAXTOK + mbase + min(tid, mcount - 1)];
    __syncthreads();

    __shared__ unsigned short As[2][128 * 32];
    __shared__ unsigned short Bs[2][TN * 32];
    const unsigned short* BT = BTconv + (size_t)egl * (768 * 3072);
    int col0 = blockIdx.x * TN;
    int wrow = (w >> 1) * 64, wcol = (w & 1) * (TN / 2);
    int lr = lane & 15, g = lane >> 4;
    f32x4 acc[4][NCF] = {};

    int ra[2], ka[2], la[2], tok_s[2];
    #pragma unroll
    for (int i = 0; i < 2; ++i) {
        int off = tid * 16 + i * 4096;
        int row = off >> 6;
        int slot = (off >> 4) & 3;
        ra[i] = row;
        ka[i] = (slot ^ ((row >> 1) & 3)) * 8;
        la[i] = off >> 1;
        tok_s[i] = toks[row];
    }
    int nt = K >> 5, cur = 0;
    #pragma unroll
    for (int i = 0; i < 2; ++i)
        gl16(A + (size_t)tok_s[i] * K + ka[i], &As[0][la[i]]);
    #pragma unroll
    for (int i = 0; i < NBS; ++i)
        gl16(BT + (size_t)(col0 + ra[i]) * K + ka[i], &Bs[0][la[i]]);

    for (int t = 0; t < nt; ++t) {
        __syncthreads();
        if (t + 1 < nt) {
            int k0 = (t + 1) << 5;
            #pragma unroll
            for (int i = 0; i < 2; ++i)
                gl16(A + (size_t)tok_s[i] * K + k0 + ka[i], &As[cur ^ 1][la[i]]);
            #pragma unroll
            for (int i = 0; i < NBS; ++i)
                gl16(BT + (size_t)(col0 + ra[i]) * K + k0 + ka[i], &Bs[cur ^ 1][la[i]]);
        }
        short8v av[4], bv[NCF];
        #pragma unroll
        for (int mr = 0; mr < 4; ++mr) {
            int row = wrow + mr * 16 + lr;
            av[mr] = *(const short8v*)&As[cur][row * 32 + (g ^ ((row >> 1) & 3)) * 8];
        }
        #pragma unroll
        for (int nc = 0; nc < NCF; ++nc) {
            int row = wcol + nc * 16 + lr;
            bv[nc] = *(const short8v*)&Bs[cur][row * 32 + (g ^ ((row >> 1) & 3)) * 8];
        }
        #pragma unroll
        for (int mr = 0; mr < 4; ++mr)
            #pragma unroll
            for (int nc = 0; nc < NCF; ++nc)
                acc[mr][nc] = __builtin_amdgcn_mfma_f32_16x16x32_bf16(
                    av[mr], bv[nc], acc[mr][nc], 0, 0, 0);
        cur ^= 1;
    }
    int rbase = g * 4;
    #pragma unroll
    for (int mr = 0; mr < 4; ++mr) {
        #pragma unroll
        for (int r = 0; r < 4; ++r) {
            int m = wrow + mr * 16 + rbase + r;
            if (m >= mcount) continue;
            int tok = toks[m];
            #pragma unroll
            for (int nc = 0; nc < NCF; ++nc) {
                int gc = col0 + wcol + nc * 16 + lr;
                float v = acc[mr][nc][r];
                if (PHASE == 1) Cb[(size_t)tok * 3072 + gc] = f2bf(geluf(v));
                else {
                    size_t idx = (size_t)tok * 768 + gc;
                    Cb[idx] = f2bf(bf2f(Cb[idx]) + gval[tok] * v);
                }
            }
        }
    }
}

// ---------------- MoE phase-2 with split-K (4 segments of 768) ----------
__global__ __launch_bounds__(256) void moe_lds2k(
    const unsigned short* __restrict__ A,       // hbuf [tok][3072]
    const unsigned short* __restrict__ BTconv,  // [egl][768][3072]
    float* __restrict__ scr,                    // [tok][768] f32 partials
    const int* __restrict__ cnt, const int* __restrict__ list, int RT)
{
    constexpr int K = 3072;
    constexpr int TN = 64;
    constexpr int NCF = 2;
    int egl = blockIdx.y / RT, rt = blockIdx.y % RT;
    int c0 = cnt[egl];
    int mbase = rt * 128;
    if (mbase >= c0) return;
    int mcount = min(128, c0 - mbase);
    __shared__ int toks[128];
    int tid = threadIdx.x, w = tid >> 6, lane = tid & 63;
    if (tid < 128) toks[tid] = list[egl * MAXTOK + mbase + min(tid, mcount - 1)];
    __syncthreads();

    __shared__ unsigned short As[2][128 * 32];
    __shared__ unsigned short Bs[2][TN * 32];
    const unsigned short* BT = BTconv + (size_t)egl * (768 * 3072);
    int col0 = blockIdx.x * TN;
    int ksbase = blockIdx.z * 768;              // K segment
    int wrow = (w >> 1) * 64, wcol = (w & 1) * (TN / 2);
    int lr = lane & 15, g = lane >> 4;
    f32x4 acc[4][NCF] = {};

    int ra[2], ka[2], la[2], tok_s[2];
    #pragma unroll
    for (int i = 0; i < 2; ++i) {
        int off = tid * 16 + i * 4096;
        int row = off >> 6;
        int slot = (off >> 4) & 3;
        ra[i] = row;
        ka[i] = (slot ^ ((row >> 1) & 3)) * 8;
        la[i] = off >> 1;
        tok_s[i] = toks[row];
    }
    int nt = 768 >> 5, cur = 0;
    #pragma unroll
    for (int i = 0; i < 2; ++i)
        gl16(A + (size_t)tok_s[i] * K + ksbase + ka[i], &As[0][la[i]]);
    gl16(BT + (size_t)(col0 + ra[0]) * K + ksbase + ka[0], &Bs[0][la[0]]);

    for (int t = 0; t < nt; ++t) {
        __syncthreads();
        if (t + 1 < nt) {
            int k0 = ksbase + ((t + 1) << 5);
            #pragma unroll
            for (int i = 0; i < 2; ++i)
                gl16(A + (size_t)tok_s[i] * K + k0 + ka[i], &As[cur ^ 1][la[i]]);
            gl16(BT + (size_t)(col0 + ra[0]) * K + k0 + ka[0], &Bs[cur ^ 1][la[0]]);
        }
        short8v av[4], bv[NCF];
        #pragma unroll
        for (int mr = 0; mr < 4; ++mr) {
            int row = wrow + mr * 16 + lr;
            av[mr] = *(const short8v*)&As[cur][row * 32 + (g ^ ((row >> 1) & 3)) * 8];
        }
        #pragma unroll
        for (int nc = 0; nc < NCF; ++nc) {
            int row = wcol + nc * 16 + lr;
            bv[nc] = *(const short8v*)&Bs[cur][row * 32 + (g ^ ((row >> 1) & 3)) * 8];
        }
        #pragma unroll
        for (int mr = 0; mr < 4; ++mr)
            #pragma unroll
            for (int nc = 0; nc < NCF; ++nc)
                acc[mr][nc] = __builtin_amdgcn_mfma_f32_16x16x32_bf16(
                    av[mr], bv[nc], acc[mr][nc], 0, 0, 0);
        cur ^= 1;
    }
    int rbase = g * 4;
    #pragma unroll
    for (int mr = 0; mr < 4; ++mr) {
        #pragma unroll
        for (int r = 0; r < 4; ++r) {
            int m = wrow + mr * 16 + rbase + r;
            if (m >= mcount) continue;
            int tok = toks[m];
            #pragma unroll
            for (int nc = 0; nc < NCF; ++nc) {
                int gc = col0 + wcol + nc * 16 + lr;
                atomicAdd(&scr[(size_t)tok * 768 + gc], acc[mr][nc][r]);
            }
        }
    }
}

// ---------------- LayerNorm (bf16 in) -> bf16 ----------------
__global__ __launch_bounds__(256) void ln_kernel(
    const unsigned short* __restrict__ X, unsigned short* __restrict__ Y, int R, int ntok,
    const float* __restrict__ mod, int modstride, int shift_chunk, int scale_chunk)
{
    int r = blockIdx.x;
    if (r >= R) return;
    const unsigned short* xr = X + (size_t)r * D;
    int tid = threadIdx.x;
    int lane = tid & 63, wid = tid >> 6;
    float v0 = bf2f(xr[tid]), v1 = bf2f(xr[tid + 256]), v2 = bf2f(xr[tid + 512]);
    float s = v0 + v1 + v2;
    float s2 = v0 * v0 + v1 * v1 + v2 * v2;
    for (int off = 32; off > 0; off >>= 1) {
        s += __shfl_xor(s, off, 64);
        s2 += __shfl_xor(s2, off, 64);
    }
    __shared__ float shs[4], shs2[4];
    if (lane == 0) { shs[wid] = s; shs2[wid] = s2; }
    __syncthreads();
    float tot = shs[0] + shs[1] + shs[2] + shs[3];
    float tot2 = shs2[0] + shs2[1] + shs2[2] + shs2[3];
    float mu = tot * (1.f / 768.f);
    float var = tot2 * (1.f / 768.f) - mu * mu;
    float rs = rsqrtf(var + 1e-6f);
    int bb = r / ntok;
    float vv[3] = {v0, v1, v2};
    #pragma unroll
    for (int j = 0; j < 3; ++j) {
        int col = tid + j * 256;
        float nrm = (vv[j] - mu) * rs;
        float y = nrm;
        if (mod) {
            float scv = mod[(size_t)bb * modstride + scale_chunk * D + col];
            float shv = mod[(size_t)bb * modstride + shift_chunk * D + col];
            y = nrm * (1.f + scv) + shv;
        }
        Y[(size_t)r * D + col] = f2bf(y);
    }
}

// ---------------- MFMA flash attention (V transposed in-kernel) ----------
__global__ __launch_bounds__(512) void attn_mfma(
    const unsigned short* __restrict__ Qp, int ldq, int qoff,
    const unsigned short* __restrict__ Kp, int ldk, int koff,
    const unsigned short* __restrict__ Vp, int ldv, int voff,
    unsigned short* __restrict__ O, int ldo,
    int Nq, int Nkv)
{
    __shared__ unsigned short Qs[128 * 64];
    __shared__ unsigned short Ks[64 * 64];
    __shared__ unsigned short Vs[64 * 64];
    __shared__ unsigned short Ps[128 * 64];
    int h = blockIdx.y, b = blockIdx.z, q0 = blockIdx.x * 128;
    int tid = threadIdx.x, w = tid >> 6, lane = tid & 63;
    int wrow = w * 16;
    int lr = lane & 15, g = lane >> 4;

    {
        int srow = tid >> 2, sc = (tid & 3) * 16;
        int gr = min(q0 + srow, Nq - 1);
        const unsigned short* qp = Qp + (size_t)(b * Nq + gr) * ldq + qoff + h * 64 + sc;
        short8v v0 = *(const short8v*)qp, v1 = *(const short8v*)(qp + 8);
        int s0 = sc >> 3;
        *(short8v*)&Qs[srow * 64 + (s0 ^ (srow & 7)) * 8] = v0;
        *(short8v*)&Qs[srow * 64 + ((s0 + 1) ^ (srow & 7)) * 8] = v1;
    }
    float m_r[4] = {-1e30f, -1e30f, -1e30f, -1e30f};
    float l_r[4] = {};
    f32x4 acc0 = {}, acc1 = {}, acc2 = {}, acc3 = {};

    for (int kv0 = 0; kv0 < Nkv; kv0 += 64) {
        {
            int t2 = tid & 255;
            int srow = t2 >> 2, sc = (t2 & 3) * 16;
            int gc = min(kv0 + srow, Nkv - 1);
            if (tid < 256) {
                const unsigned short* kp = Kp + (size_t)(b * Nkv + gc) * ldk + koff + h * 64 + sc;
                short8v v0 = *(const short8v*)kp, v1 = *(const short8v*)(kp + 8);
                int s0 = sc >> 3;
                *(short8v*)&Ks[srow * 64 + (s0 ^ (srow & 7)) * 8] = v0;
                *(short8v*)&Ks[srow * 64 + ((s0 + 1) ^ (srow & 7)) * 8] = v1;
            } else {
                const unsigned short* vp = Vp + (size_t)(b * Nkv + gc) * ldv + voff + h * 64 + sc;
                #pragma unroll
                for (int j = 0; j < 16; ++j) {
                    int d = sc + j;
                    Vs[d * 64 + (((srow >> 3) ^ (d & 7)) * 8) + (srow & 7)] = vp[j];
                }
            }
        }
        __syncthreads();
        short8v aq0, aq1;
        {
            int row = wrow + lr;
            aq0 = *(const short8v*)&Qs[row * 64 + ((0 + g) ^ (row & 7)) * 8];
            aq1 = *(const short8v*)&Qs[row * 64 + ((4 + g) ^ (row & 7)) * 8];
        }
        f32x4 sf[4];
        #pragma unroll
        for (int nc = 0; nc < 4; ++nc) {
            int row = nc * 16 + lr;
            short8v bk0 = *(const short8v*)&Ks[row * 64 + ((0 + g) ^ (row & 7)) * 8];
            short8v bk1 = *(const short8v*)&Ks[row * 64 + ((4 + g) ^ (row & 7)) * 8];
            f32x4 z = {};
            z = __builtin_amdgcn_mfma_f32_16x16x32_bf16(aq0, bk0, z, 0, 0, 0);
            sf[nc] = __builtin_amdgcn_mfma_f32_16x16x32_bf16(aq1, bk1, z, 0, 0, 0);
        }
        bool val0 = (kv0 + 0 * 16 + lr) < Nkv;
        bool val1 = (kv0 + 1 * 16 + lr) < Nkv;
        bool val2 = (kv0 + 2 * 16 + lr) < Nkv;
        bool val3 = (kv0 + 3 * 16 + lr) < Nkv;
        float fs[4];
        #pragma unroll
        for (int r = 0; r < 4; ++r) {
            float s0 = val0 ? sf[0][r] : -1e30f;
            float s1 = val1 ? sf[1][r] : -1e30f;
            float s2 = val2 ? sf[2][r] : -1e30f;
            float s3 = val3 ? sf[3][r] : -1e30f;
            float mx = fmaxf(fmaxf(s0, s1), fmaxf(s2, s3));
            mx = fmaxf(mx, __shfl_xor(mx, 1, 64));
            mx = fmaxf(mx, __shfl_xor(mx, 2, 64));
            mx = fmaxf(mx, __shfl_xor(mx, 4, 64));
            mx = fmaxf(mx, __shfl_xor(mx, 8, 64));
            float mn = fmaxf(m_r[r], mx);
            fs[r] = __expf(m_r[r] - mn);
            m_r[r] = mn;
            float p0 = __expf(s0 - mn), p1 = __expf(s1 - mn);
            float p2 = __expf(s2 - mn), p3 = __expf(s3 - mn);
            float rsum = p0 + p1 + p2 + p3;
            rsum += __shfl_xor(rsum, 1, 64);
            rsum += __shfl_xor(rsum, 2, 64);
            rsum += __shfl_xor(rsum, 4, 64);
            rsum += __shfl_xor(rsum, 8, 64);
            l_r[r] = l_r[r] * fs[r] + rsum;
            int ql = wrow + g * 4 + r;
            int base = ql * 64;
            int x7 = ql & 7;
            Ps[base + (((0 * 16 + lr) >> 3) ^ x7) * 8 + (lr & 7)] = f2bf(p0);
            Ps[base + (((1 * 16 + lr) >> 3) ^ x7) * 8 + (lr & 7)] = f2bf(p1);
            Ps[base + (((2 * 16 + lr) >> 3) ^ x7) * 8 + (lr & 7)] = f2bf(p2);
            Ps[base + (((3 * 16 + lr) >> 3) ^ x7) * 8 + (lr & 7)] = f2bf(p3);
            acc0[r] *= fs[r]; acc1[r] *= fs[r]; acc2[r] *= fs[r]; acc3[r] *= fs[r];
        }
        __syncthreads();
        short8v ap0, ap1;
        {
            int row = wrow + lr;
            ap0 = *(const short8v*)&Ps[row * 64 + ((0 + g) ^ (row & 7)) * 8];
            ap1 = *(const short8v*)&Ps[row * 64 + ((4 + g) ^ (row & 7)) * 8];
        }
        {
            int row = 0 * 16 + lr;
            short8v b0 = *(const short8v*)&Vs[row * 64 + ((0 + g) ^ (row & 7)) * 8];
            short8v b1 = *(const short8v*)&Vs[row * 64 + ((4 + g) ^ (row & 7)) * 8];
            acc0 = __builtin_amdgcn_mfma_f32_16x16x32_bf16(ap0, b0, acc0, 0, 0, 0);
            acc0 = __builtin_amdgcn_mfma_f32_16x16x32_bf16(ap1, b1, acc0, 0, 0, 0);
        }
        {
            int row = 1 * 16 + lr;
            short8v b0 = *(const short8v*)&Vs[row * 64 + ((0 + g) ^ (row & 7)) * 8];
            short8v b1 = *(const short8v*)&Vs[row * 64 + ((4 + g) ^ (row & 7)) * 8];
            acc1 = __builtin_amdgcn_mfma_f32_16x16x32_bf16(ap0, b0, acc1, 0, 0, 0);
            acc1 = __builtin_amdgcn_mfma_f32_16x16x32_bf16(ap1, b1, acc1, 0, 0, 0);
        }
        {
            int row = 2 * 16 + lr;
            short8v b0 = *(const short8v*)&Vs[row * 64 + ((0 + g) ^ (row & 7)) * 8];
            short8v b1 = *(const short8v*)&Vs[row * 64 + ((4 + g) ^ (row & 7)) * 8];
            acc2 = __builtin_amdgcn_mfma_f32_16x16x32_bf16(ap0, b0, acc2, 0, 0, 0);
            acc2 = __builtin_amdgcn_mfma_f32_16x16x32_bf16(ap1, b1, acc2, 0, 0, 0);
        }
        {
            int row = 3 * 16 + lr;
            short8v b0 = *(const short8v*)&Vs[row * 64 + ((0 + g) ^ (row & 7)) * 8];
            short8v b1 = *(const short8v*)&Vs[row * 64 + ((4 + g) ^ (row & 7)) * 8];
            acc3 = __builtin_amdgcn_mfma_f32_16x16x32_bf16(ap0, b0, acc3, 0, 0, 0);
            acc3 = __builtin_amdgcn_mfma_f32_16x16x32_bf16(ap1, b1, acc3, 0, 0, 0);
        }
        __syncthreads();
    }
    #pragma unroll
    for (int r = 0; r < 4; ++r) {
        int ql = wrow + g * 4 + r;
        if (q0 + ql >= Nq) continue;
        float rl = 1.f / l_r[r];
        unsigned short* op = O + (size_t)(b * Nq + q0 + ql) * ldo + h * 64 + lr;
        op[0]  = f2bf(acc0[r] * rl);
        op[16] = f2bf(acc1[r] * rl);
        op[32] = f2bf(acc2[r] * rl);
        op[48] = f2bf(acc3[r] * rl);
    }
}

// ---------------- MoE router ----------------
__global__ __launch_bounds__(64) void router_kernel(
    const unsigned short* __restrict__ X, const float* __restrict__ WrBase,
    int* __restrict__ idx, float* __restrict__ gval)
{
    int tkn = blockIdx.x; int lane = threadIdx.x;
    int grp = (tkn >= 768) ? 2 : (tkn >= 512 ? 1 : 0);
    const float* Wr = WrBase + (size_t)grp * D * NEXP;
    const unsigned short* xr = X + (size_t)tkn * D;
    float p0 = 0, p1 = 0, p2 = 0, p3 = 0;
    for (int dd = lane; dd < D; dd += 64) {
        float xv = bf2f(xr[dd]);
        const float* wq = Wr + dd * 4;
        p0 += xv * wq[0]; p1 += xv * wq[1]; p2 += xv * wq[2]; p3 += xv * wq[3];
    }
    for (int off = 32; off > 0; off >>= 1) {
        p0 += __shfl_xor(p0, off, 64); p1 += __shfl_xor(p1, off, 64);
        p2 += __shfl_xor(p2, off, 64); p3 += __shfl_xor(p3, off, 64);
    }
    if (lane == 0) {
        float best = p0; int e = 0;
        if (p1 > best) { best = p1; e = 1; }
        if (p2 > best) { best = p2; e = 2; }
        if (p3 > best) { best = p3; e = 3; }
        float sum = expf(p0 - best) + expf(p1 - best) + expf(p2 - best) + expf(p3 - best);
        idx[tkn] = grp * 4 + e;
        gval[tkn] = 1.f / sum;
    }
}

__global__ __launch_bounds__(256) void scatter_kernel(
    const int* __restrict__ idx, int* __restrict__ cnt,
    int* __restrict__ list, int ntok)
{
    __shared__ int lcnt[12];
    int tid = threadIdx.x;
    if (tid < 12) lcnt[tid] = 0;
    __syncthreads();
    for (int i = tid; i < ntok; i += 256) {
        int e = idx[i];
        int pos = atomicAdd(&lcnt[e], 1);
        list[e * MAXTOK + pos] = i;
    }
    __syncthreads();
    if (tid < 12) cnt[tid] = lcnt[tid];
}

// ---------------- concat (traj f32 + groups bf16 -> x bf16) ----------------
__global__ void concat_kernel(const float* __restrict__ traj, const unsigned short* __restrict__ a,
                              const unsigned short* __restrict__ bg, const unsigned short* __restrict__ cg,
                              unsigned short* __restrict__ x, int total)
{
    int i = blockIdx.x * blockDim.x + threadIdx.x;
    if (i >= total) return;
    int col = i % D;
    int r = i / D;
    int n = r % NTOK, b = r / NTOK;
    unsigned short v;
    if (n < 256)      v = f2bf(traj[((size_t)b * 256 + n) * D + col]);
    else if (n < 320) v = a[((size_t)b * 64 + (n - 256)) * D + col];
    else if (n < 352) v = bg[((size_t)b * 32 + (n - 320)) * D + col];
    else              v = cg[((size_t)b * 192 + (n - 352)) * D + col];
    x[i] = v;
}

// ---------------- output head ----------------
__global__ void head_prep(const float* __restrict__ W, unsigned short* __restrict__ WT14) {
    int i = blockIdx.x * blockDim.x + threadIdx.x;
    if (i >= 14 * 768) return;
    int o = i / 768, d = i % 768;
    WT14[i] = f2bf(W[d * 14 + o]);
}

__global__ __launch_bounds__(64) void head_kernel(
    const unsigned short* __restrict__ lnb, const unsigned short* __restrict__ WT14,
    const float* __restrict__ bias, float* __restrict__ out)
{
    int r = blockIdx.x;
    int b = r >> 8, n = r & 255;
    const unsigned short* hrow = lnb + (size_t)(b * NTOK + n) * D;
    int l = threadIdx.x;
    if (l >= 56) return;
    int o = l >> 2, p = l & 3;
    const unsigned short* hp = hrow + p * 192;
    const unsigned short* wp = WT14 + o * 768 + p * 192;
    float acc = 0.f;
    for (int i = 0; i < 192; i += 8) {
        short8v hv = *(const short8v*)(hp + i);
        short8v wv = *(const short8v*)(wp + i);
        #pragma unroll
        for (int j = 0; j < 8; ++j)
            acc += bf2f((unsigned short)hv[j]) * bf2f((unsigned short)wv[j]);
    }
    acc += __shfl_xor(acc, 1, 64);
    acc += __shfl_xor(acc, 2, 64);
    if (p == 0) out[(size_t)r * 14 + o] = acc + bias[o];
}

// ---------------- host helpers ----------------
static inline void tcvt(const float* W, unsigned short* WT, int K, int N, int z, hipStream_t s) {
    transpose_cvt<<<dim3(N / 64, K / 64, z), 256, 0, s>>>(W, WT, K, N);
}
// TM=64 everywhere: max grid occupancy hides the 2-buffer barrier drain
// (rounds 12/18/19 lever; qkv 306->1224 blocks, mlp1 408->1632 blocks).
static inline void g_bf(int act, const unsigned short* A, const unsigned short* BT,
                        const float* bias, unsigned short* C, int ldc,
                        int M, int N, int K, int qcols, hipStream_t s)
{
    if (N != 768) {
        dim3 g(N / 128, M / 64);
        if (act == 2) gemm_lds<2, 1, 128, 64><<<g, 256, 0, s>>>(A, BT, bias, nullptr, C, ldc, K, qcols, nullptr, 0, 0, 1, 1 << 30);
        else          gemm_lds<0, 1, 128, 64><<<g, 256, 0, s>>>(A, BT, bias, nullptr, C, ldc, K, qcols, nullptr, 0, 0, 1, 1 << 30);
    } else {
        dim3 g(N / 64, M / 64);
        if (act == 2) gemm_lds<2, 1, 64, 64><<<g, 256, 0, s>>>(A, BT, bias, nullptr, C, ldc, K, qcols, nullptr, 0, 0, 1, 1 << 30);
        else          gemm_lds<0, 1, 64, 64><<<g, 256, 0, s>>>(A, BT, bias, nullptr, C, ldc, K, qcols, nullptr, 0, 0, 1, 1 << 30);
    }
}
static inline void g_res(const unsigned short* A, const unsigned short* BT,
                         const float* bias, unsigned short* C, int ldc, int M, int N, int K,
                         const float* mod, int modstride, int gchunk, int ntok, hipStream_t s)
{
    dim3 g(N / 64, M / 64);
    gemm_lds<0, 2, 64, 64><<<g, 256, 0, s>>>(A, BT, bias, nullptr, C, ldc, K, 0, mod, modstride, gchunk, ntok, 1 << 30);
}

extern "C" void kernel_launch(void* const* d_in, const int* in_sizes, int n_in,
                              void* d_out, int out_size, void* d_ws, size_t ws_size,
                              hipStream_t stream)
{
    const float* x_traj   = (const float*)d_in[0];
    const int*   t_arr    = (const int*)d_in[1];
    const float* tokA     = (const float*)d_in[2];
    const float* tokB     = (const float*)d_in[3];
    const float* tokC     = (const float*)d_in[4];
    const float* W_traj   = (const float*)d_in[5];
    const float* b_traj   = (const float*)d_in[6];
    const float* W_ftime  = (const float*)d_in[7];
    const float* Wt1      = (const float*)d_in[8];
    const float* bt1      = (const float*)d_in[9];
    const float* Wt2      = (const float*)d_in[10];
    const float* bt2      = (const float*)d_in[11];
    const float* moe_attn = (const float*)d_in[12];
    const float* moe_rout = (const float*)d_in[13];
    const float* moe_W1   = (const float*)d_in[14];
    const float* moe_W2   = (const float*)d_in[15];
    const float* dit_qkv  = (const float*)d_in[16];
    const float* dit_qkvb = (const float*)d_in[17];
    const float* dit_proj = (const float*)d_in[18];
    const float* dit_projb= (const float*)d_in[19];
    const float* dit_mlp1 = (const float*)d_in[20];
    const float* dit_mlp1b= (const float*)d_in[21];
    const float* dit_mlp2 = (const float*)d_in[22];
    const float* dit_mlp2b= (const float*)d_in[23];
    const float* dit_ada  = (const float*)d_in[24];
    const float* dit_adab = (const float*)d_in[25];
    const float* out_adaW = (const float*)d_in[26];
    const float* out_adab = (const float*)d_in[27];
    const float* out_W    = (const float*)d_in[28];
    const float* out_b    = (const float*)d_in[29];
    float* out = (float*)d_out;
    float* ws = (float*)d_ws;

    const size_t o_cnt  = 14336;
    const size_t o_idx  = 14400;
    const size_t o_gval = 16704;
    const size_t o_list = 19008;
    const size_t o_traj = 66624;             // f32 traj; later mod buffers
    const size_t o_a    = 1639488;           // bf16 a|bg|cg = 2304x768 shorts
    const size_t o_x    = 3408960;           // bf16 x
    const size_t o_lnb  = 6751296;
    const size_t o_qkvb = 8422464;
    const size_t o_attnO= 13435968;
    const size_t o_h    = 15107136;
    const size_t o_wt   = 24151104;
    const size_t o_wt14 = 28869696;
    const size_t o_tembP= 28875072;
    const size_t o_ub   = 28891456;
    const size_t o_scb  = 28940608;
    const size_t o_mod  = o_traj;
    const size_t o_mod2 = o_traj + 221184;

    const size_t o_wqkv  = 29000000;
    const size_t o_wproj = 34308416;
    const size_t o_wmlp1 = 36077888;
    const size_t o_wmlp2 = 43155776;
    const size_t o_wada  = 50233664;
    const size_t o_wada2 = 60850496;
    const size_t o_wcross= 61440320;
    const size_t o_wmoe1 = 66158912;
    const size_t o_wmoe2 = 94470464;
    const bool bigw = ws_size >= (size_t)123000000 * 4;

    int* cnt_p  = (int*)(ws + o_cnt);
    int* idx_p  = (int*)(ws + o_idx);
    int* list_p = (int*)(ws + o_list);
    float* gval_p = ws + o_gval;
    unsigned short* abf  = (unsigned short*)(ws + o_a);
    unsigned short* bgbf = abf + 512 * 768;
    unsigned short* cgbf = abf + 768 * 768;
    unsigned short* xbf  = (unsigned short*)(ws + o_x);
    unsigned short* lnb  = (unsigned short*)(ws + o_lnb);
    unsigned short* qkvb = (unsigned short*)(ws + o_qkvb);
    unsigned short* attO = (unsigned short*)(ws + o_attnO);
    unsigned short* hbuf = (unsigned short*)(ws + o_h);
    unsigned short* wt   = (unsigned short*)(ws + o_wt);
    unsigned short* wt14 = (unsigned short*)(ws + o_wt14);
    unsigned short* tembP= (unsigned short*)(ws + o_tembP);
    unsigned short* ub   = (unsigned short*)(ws + o_ub);
    unsigned short* scb  = (unsigned short*)(ws + o_scb);
    unsigned short* wqkvS = (unsigned short*)(ws + o_wqkv);
    unsigned short* wprojS= (unsigned short*)(ws + o_wproj);
    unsigned short* wmlp1S= (unsigned short*)(ws + o_wmlp1);
    unsigned short* wmlp2S= (unsigned short*)(ws + o_wmlp2);
    unsigned short* wadaS = (unsigned short*)(ws + o_wada);
    unsigned short* wada2S= (unsigned short*)(ws + o_wada2);
    unsigned short* wcrossS=(unsigned short*)(ws + o_wcross);
    unsigned short* wmoe1S= (unsigned short*)(ws + o_wmoe1);
    unsigned short* wmoe2S= (unsigned short*)(ws + o_wmoe2);
    unsigned short* c_q  = qkvb;
    unsigned short* c_kv = qkvb + 1179648;
    float* scr = ws + o_qkvb;   // split-K scratch (2304*768 f32) — qkvb region, free during MoE

    const size_t WSZ = (size_t)D * D;

    gemm_act<0><<<dim3(12, 32), 256, 0, stream>>>(x_traj, 7, W_traj, D, b_traj,
                                                  ws + o_traj, D, BATCH * TTRAJ, D, 7);
    add_ftime<<<(BATCH * TTRAJ * D + 255) / 256, 256, 0, stream>>>(ws + o_traj, W_ftime, BATCH * TTRAJ * D);

    cvt_bf16<<<(512 * 768 / 8 + 255) / 256, 256, 0, stream>>>(tokA, abf, 512 * 768 / 8);
    cvt_bf16<<<(256 * 768 / 8 + 255) / 256, 256, 0, stream>>>(tokB, bgbf, 256 * 768 / 8);
    cvt_bf16<<<(1536 * 768 / 8 + 255) / 256, 256, 0, stream>>>(tokC, cgbf, 1536 * 768 / 8);
    head_prep<<<42, 256, 0, stream>>>(out_W, wt14);

    if (bigw) {
        tcvt(dit_qkv,  wqkvS,  D, 3 * D, DEPTH, stream);
        tcvt(dit_proj, wprojS, D, D, DEPTH, stream);
        tcvt(dit_mlp1, wmlp1S, D, FF, DEPTH, stream);
        tcvt(dit_mlp2, wmlp2S, FF, D, DEPTH, stream);
        tcvt(dit_ada,  wadaS,  D, 6 * D, DEPTH, stream);
        tcvt(out_adaW, wada2S, D, 2 * D, 1, stream);
        tcvt(moe_attn, wcrossS, D, D, NBLK * 2 * 4, stream);
        tcvt(moe_W1,   wmoe1S, D, FF, NBLK * 3 * NEXP, stream);
        tcvt(moe_W2,   wmoe2S, FF, D, NBLK * 3 * NEXP, stream);
    }

    timestep_kernel<<<128, 256, 0, stream>>>(t_arr, tembP);
    tcvt(Wt1, wt, 256, D, 1, stream);
    gemm_lds<1, 1, 64, 128><<<dim3(12, 1), 256, 0, stream>>>(
        tembP, wt, bt1, nullptr, ub, D, 256, 0, nullptr, 0, 0, 1, 128);
    tcvt(Wt2, wt, D, D, 1, stream);
    gemm_lds<1, 1, 64, 128><<<dim3(12, 1), 256, 0, stream>>>(
        ub, wt, bt2, nullptr, scb, D, D, 0, nullptr, 0, 0, 1, 128);

    for (int i = 0; i < NBLK; ++i) {
        {
            const unsigned short* Wc;
            if (bigw) Wc = wcrossS + (size_t)(i * 2 + 0) * 4 * WSZ;
            else { tcvt(moe_attn + (size_t)(i * 2 + 0) * 4 * WSZ, wt, D, D, 4, stream); Wc = wt; }
            ln_kernel<<<BATCH * NC, 256, 0, stream>>>(cgbf, lnb, BATCH * NC, 1, nullptr, 0, 0, 0);
            g_bf(0, lnb, Wc, nullptr, c_q, D, BATCH * NC, D, D, 768, stream);
            g_bf(0, abf, Wc + 1 * WSZ, nullptr, c_kv, 2 * D, BATCH * NA, 2 * D, D, 0, stream);
            attn_mfma<<<dim3((NC + 127) / 128, NH, BATCH), 512, 0, stream>>>(
                c_q, D, 0, c_kv, 2 * D, 0, c_kv, 2 * D, D, attO, D, NC, NA);
            g_res(attO, Wc + 3 * WSZ, nullptr, cgbf, D, BATCH * NC, D, D, nullptr, 0, 0, 1, stream);
        }
        {
            const unsigned short* Wc;
            if (bigw) Wc = wcrossS + (size_t)(i * 2 + 1) * 4 * WSZ;
            else { tcvt(moe_attn + (size_t)(i * 2 + 1) * 4 * WSZ, wt, D, D, 4, stream); Wc = wt; }
            ln_kernel<<<BATCH * NB, 256, 0, stream>>>(bgbf, lnb, BATCH * NB, 1, nullptr, 0, 0, 0);
            g_bf(0, lnb, Wc, nullptr, c_q, D, BATCH * NB, D, D, 768, stream);
            g_bf(0, cgbf, Wc + 1 * WSZ, nullptr, c_kv, 2 * D, BATCH * NC, 2 * D, D, 0, stream);
            attn_mfma<<<dim3(1, NH, BATCH), 512, 0, stream>>>(
                c_q, D, 0, c_kv, 2 * D, 0, c_kv, 2 * D, D, attO, D, NB, NC);
            g_res(attO, Wc + 3 * WSZ, nullptr, bgbf, D, BATCH * NB, D, D, nullptr, 0, 0, 1, stream);
        }
        ln_kernel<<<MOER, 256, 0, stream>>>(abf, lnb, MOER, 1, nullptr, 0, 0, 0);
        router_kernel<<<MOER, 64, 0, stream>>>(lnb, moe_rout + (size_t)(i * 3) * D * NEXP, idx_p, gval_p);
        scatter_kernel<<<1, 256, 0, stream>>>(idx_p, cnt_p, list_p, MOER);
        const int RT = 12;
        if (bigw) {
            moe_lds<1><<<dim3(24, 12 * RT), 256, 0, stream>>>(
                lnb, wmoe1S + (size_t)(i * 3) * NEXP * D * FF, hbuf,
                cnt_p, list_p, gval_p, RT, 0);
            zero_f32<<<(442368 + 255) / 256, 256, 0, stream>>>(scr, 442368);
            moe_lds2k<<<dim3(12, 12 * RT, 4), 256, 0, stream>>>(
                hbuf, wmoe2S + (size_t)(i * 3) * NEXP * D * FF, scr,
                cnt_p, list_p, RT);
            moe_fin<<<(442368 + 255) / 256, 256, 0, stream>>>(scr, gval_p, abf, 442368);
        } else {
            for (int g = 0; g < 3; ++g) {
                tcvt(moe_W1 + (size_t)(i * 3 + g) * NEXP * D * FF, wt, D, FF, NEXP, stream);
                moe_lds<1><<<dim3(24, 4 * RT), 256, 0, stream>>>(
                    lnb, wt, hbuf, cnt_p, list_p, gval_p, RT, g * 4);
                tcvt(moe_W2 + (size_t)(i * 3 + g) * NEXP * FF * D, wt, FF, D, NEXP, stream);
                moe_lds<2><<<dim3(12, 4 * RT), 256, 0, stream>>>(
                    hbuf, wt, abf, cnt_p, list_p, gval_p, RT, g * 4);
            }
        }
    }

    concat_kernel<<<(BATCH * NTOK * D + 255) / 256, 256, 0, stream>>>(
        ws + o_traj, abf, bgbf, cgbf, xbf, BATCH * NTOK * D);

    if (bigw) {
        gemm_lds<0, 0, 128, 128><<<dim3(36, 1, DEPTH), 256, 0, stream>>>(
            scb, wadaS, dit_adab, ws + o_mod, nullptr, 6 * D, D, 0,
            nullptr, 0, 0, 1, 8,
            (size_t)D * 6 * D, (size_t)6 * D, (size_t)8 * 6 * D);
        gemm_lds<0, 0, 128, 128><<<dim3(12, 1), 256, 0, stream>>>(
            scb, wada2S, out_adab, ws + o_mod2, nullptr, 2 * D, D, 0, nullptr, 0, 0, 1, 8);
    } else {
        for (int i = 0; i < DEPTH; ++i) {
            tcvt(dit_ada + (size_t)i * D * 6 * D, wt, D, 6 * D, 1, stream);
            gemm_lds<0, 0, 128, 128><<<dim3(36, 1), 256, 0, stream>>>(
                scb, wt, dit_adab + (size_t)i * 6 * D, ws + o_mod + (size_t)i * 8 * 6 * D,
                nullptr, 6 * D, D, 0, nullptr, 0, 0, 1, 8);
        }
        tcvt(out_adaW, wt, D, 2 * D, 1, stream);
        gemm_lds<0, 0, 128, 128><<<dim3(12, 1), 256, 0, stream>>>(
            scb, wt, out_adab, ws + o_mod2, nullptr, 2 * D, D, 0, nullptr, 0, 0, 1, 8);
    }

    const int R = BATCH * NTOK;   // 4352 = 17*256
    for (int i = 0; i < DEPTH; ++i) {
        const float* mod_l = ws + o_mod + (size_t)i * 8 * 6 * D;
        const unsigned short *Wq = nullptr, *Wp = nullptr, *Wm1 = nullptr, *Wm2 = nullptr;
        if (bigw) {
            Wq  = wqkvS  + (size_t)i * D * 3 * D;
            Wp  = wprojS + (size_t)i * D * D;
            Wm1 = wmlp1S + (size_t)i * D * FF;
            Wm2 = wmlp2S + (size_t)i * D * FF;
        }
        ln_kernel<<<R, 256, 0, stream>>>(xbf, lnb, R, NTOK, mod_l, 6 * D, 0, 1);
        if (!bigw) { tcvt(dit_qkv + (size_t)i * D * 3 * D, wt, D, 3 * D, 1, stream); Wq = wt; }
        g_bf(0, lnb, Wq, dit_qkvb + (size_t)i * 3 * D, qkvb, 3 * D, R, 3 * D, D, 768, stream);
        attn_mfma<<<dim3((NTOK + 127) / 128, NH, BATCH), 512, 0, stream>>>(
            qkvb, 3 * D, 0, qkvb, 3 * D, D, qkvb, 3 * D, 2 * D, attO, D, NTOK, NTOK);
        if (!bigw) { tcvt(dit_proj + (size_t)i * D * D, wt, D, D, 1, stream); Wp = wt; }
        g_res(attO, Wp, dit_projb + (size_t)i * D, xbf, D, R, D, D,
              mod_l, 6 * D, 2, NTOK, stream);
        ln_kernel<<<R, 256, 0, stream>>>(xbf, lnb, R, NTOK, mod_l, 6 * D, 3, 4);
        if (!bigw) { tcvt(dit_mlp1 + (size_t)i * D * FF, wt, D, FF, 1, stream); Wm1 = wt; }
        g_bf(2, lnb, Wm1, dit_mlp1b + (size_t)i * FF, hbuf, FF, R, FF, D, 0, stream);
        if (!bigw) { tcvt(dit_mlp2 + (size_t)i * FF * D, wt, FF, D, 1, stream); Wm2 = wt; }
        g_res(hbuf, Wm2, dit_mlp2b + (size_t)i * D, xbf, D, R, D, FF,
              mod_l, 6 * D, 5, NTOK, stream);
    }

    ln_kernel<<<R, 256, 0, stream>>>(xbf, lnb, R, NTOK, ws + o_mod2, 2 * D, 0, 1);
    head_kernel<<<BATCH * TTRAJ, 64, 0, stream>>>(lnb, wt14, out_b, out);
}

// Round 21
// 2156.876 us; speedup vs baseline: 1.0549x; 1.0549x over previous
//
#include <hip/hip_runtime.h>
#include <hip/hip_bf16.h>
#include <math.h>

#define D 768
#define NH 12
#define HD 64
#define NEXP 4
#define FF 3072
#define NBLK 2
#define DEPTH 6
#define NA 64
#define NB 32
#define NC 192
#define BATCH 8
#define TTRAJ 256
#define NTOK 544
#define MAXTOK 1536
#define MOER 2304

typedef __attribute__((ext_vector_type(8))) short short8v;
typedef __attribute__((ext_vector_type(4))) float f32x4;

__device__ __forceinline__ float siluf(float v) { return v / (1.f + expf(-v)); }
__device__ __forceinline__ float geluf(float v) {
    float u = 0.7978845608028654f * (v + 0.044715f * v * v * v);
    return 0.5f * v * (1.f + tanhf(u));
}
__device__ __forceinline__ unsigned short f2bf(float f) {
    union { float f; unsigned u; } v; v.f = f;
    unsigned r = v.u + 0x7fffu + ((v.u >> 16) & 1u);
    return (unsigned short)(r >> 16);
}
__device__ __forceinline__ float bf2f(unsigned short u) {
    union { unsigned u; float f; } v; v.u = ((unsigned)u) << 16; return v.f;
}
__device__ __forceinline__ void gl16(const unsigned short* g, unsigned short* l) {
    __builtin_amdgcn_global_load_lds(
        (const __attribute__((address_space(1))) void*)g,
        (__attribute__((address_space(3))) void*)l, 16, 0, 0);
}

// ---------------- timestep embedding ----------------
__global__ void timestep_kernel(const int* __restrict__ t, unsigned short* __restrict__ tembP) {
    int i = blockIdx.x * blockDim.x + threadIdx.x;
    if (i >= 128 * 256) return;
    int b = i >> 8, j = i & 255;
    float v = 0.f;
    if (b < BATCH) {
        int jj = (j & 127);
        float freq = expf(-logf(10000.f) * (float)jj / 128.f);
        float ang = (float)t[b] * freq;
        v = (j < 128) ? cosf(ang) : sinf(ang);
    }
    tembP[i] = f2bf(v);
}

__global__ void add_ftime(float* __restrict__ traj, const float* __restrict__ wf, int total) {
    int i = blockIdx.x * blockDim.x + threadIdx.x;
    if (i >= total) return;
    int col = i % D;
    int n = (i / D) % TTRAJ;
    traj[i] += wf[(n & 7) * D + col];
}

__global__ void cvt_bf16(const float* __restrict__ in, unsigned short* __restrict__ out, int n8) {
    int i = blockIdx.x * blockDim.x + threadIdx.x;
    if (i >= n8) return;
    float4 a = *(const float4*)(in + i * 8);
    float4 b = *(const float4*)(in + i * 8 + 4);
    unsigned short t[8] = {f2bf(a.x), f2bf(a.y), f2bf(a.z), f2bf(a.w),
                           f2bf(b.x), f2bf(b.y), f2bf(b.z), f2bf(b.w)};
    *(short8v*)(out + i * 8) = *(short8v*)t;
}

__global__ void zero_f32(float* __restrict__ p, int n4) {
    int i = blockIdx.x * blockDim.x + threadIdx.x;
    if (i < n4) *(float4*)(p + (size_t)i * 4) = make_float4(0.f, 0.f, 0.f, 0.f);
}

// finalize split-K MoE phase2: abf += gval * scratch
__global__ void moe_fin(const float* __restrict__ scr, const float* __restrict__ gval,
                        unsigned short* __restrict__ abf, int total4) {
    int i = blockIdx.x * blockDim.x + threadIdx.x;
    if (i >= total4) return;
    size_t base = (size_t)i * 4;
    int tok = (int)(base / 768);
    float g = gval[tok];
    float4 s = *(const float4*)(scr + base);
    unsigned short* p = abf + base;
    p[0] = f2bf(bf2f(p[0]) + g * s.x);
    p[1] = f2bf(bf2f(p[1]) + g * s.y);
    p[2] = f2bf(bf2f(p[2]) + g * s.z);
    p[3] = f2bf(bf2f(p[3]) + g * s.w);
}

// ---------------- small f32 GEMM (traj embed, K=7) ----------------
template<int ACT>
__global__ __launch_bounds__(256) void gemm_act(
    const float* __restrict__ A, int lda,
    const float* __restrict__ B, int ldb,
    const float* __restrict__ bias,
    float* __restrict__ C, int ldc,
    int M, int N, int K)
{
    __shared__ float As[16][65];
    __shared__ float Bs[16][65];
    int tid = threadIdx.x;
    int tx = tid & 15, ty = tid >> 4;
    int row0 = blockIdx.y * 64, col0 = blockIdx.x * 64;
    float acc[4][4] = {};
    for (int k0 = 0; k0 < K; k0 += 16) {
        #pragma unroll
        for (int i = 0; i < 4; ++i) {
            int e = tid + 256 * i; int m = e >> 4; int kk = e & 15;
            int gr = row0 + m, gk = k0 + kk;
            As[kk][m] = (gr < M && gk < K) ? A[(size_t)gr * lda + gk] : 0.f;
        }
        #pragma unroll
        for (int i = 0; i < 4; ++i) {
            int e = tid + 256 * i; int kk = e >> 6; int n = e & 63;
            int gk = k0 + kk, gc = col0 + n;
            Bs[kk][n] = (gk < K && gc < N) ? B[(size_t)gk * ldb + gc] : 0.f;
        }
        __syncthreads();
        #pragma unroll
        for (int kk = 0; kk < 16; ++kk) {
            float a[4], bv[4];
            #pragma unroll
            for (int i = 0; i < 4; ++i) a[i] = As[kk][ty * 4 + i];
            #pragma unroll
            for (int j = 0; j < 4; ++j) bv[j] = Bs[kk][tx * 4 + j];
            #pragma unroll
            for (int i = 0; i < 4; ++i)
                #pragma unroll
                for (int j = 0; j < 4; ++j) acc[i][j] += a[i] * bv[j];
        }
        __syncthreads();
    }
    #pragma unroll
    for (int i = 0; i < 4; ++i) {
        int gr = row0 + ty * 4 + i; if (gr >= M) continue;
        #pragma unroll
        for (int j = 0; j < 4; ++j) {
            int gc = col0 + tx * 4 + j; if (gc >= N) continue;
            float v = acc[i][j] + (bias ? bias[gc] : 0.f);
            if (ACT == 1) v = siluf(v);
            if (ACT == 2) v = geluf(v);
            C[(size_t)gr * ldc + gc] = v;
        }
    }
}

// ---------------- weight transpose + cvt ----------------
__global__ __launch_bounds__(256) void transpose_cvt(
    const float* __restrict__ in, unsigned short* __restrict__ out, int K, int N)
{
    __shared__ unsigned short Ls[64][72];
    const float* src = in + (size_t)blockIdx.z * K * N;
    unsigned short* dst = out + (size_t)blockIdx.z * K * N;
    int k0 = blockIdx.y * 64, n0 = blockIdx.x * 64;
    int tid = threadIdx.x;
    int r = tid >> 2, c0 = (tid & 3) * 16;
    {
        const float* sp = src + (size_t)(k0 + r) * N + n0 + c0;
        #pragma unroll
        for (int j = 0; j < 16; j += 4) {
            float4 f = *(const float4*)(sp + j);
            Ls[c0 + j + 0][r] = f2bf(f.x);
            Ls[c0 + j + 1][r] = f2bf(f.y);
            Ls[c0 + j + 2][r] = f2bf(f.z);
            Ls[c0 + j + 3][r] = f2bf(f.w);
        }
    }
    __syncthreads();
    {
        unsigned short tmp[16];
        #pragma unroll
        for (int j = 0; j < 16; ++j) tmp[j] = Ls[r][c0 + j];
        unsigned short* dp = dst + (size_t)(n0 + r) * K + k0 + c0;
        *(short8v*)dp = *(short8v*)tmp;
        *(short8v*)(dp + 8) = *(short8v*)(tmp + 8);
    }
}

// ---------------- MFMA GEMM: BK=32, dbuf, TM=128/64, TN=128/64, 4 waves ----
// OUT: 0 f32, 1 bf16 (+qscale), 2 bf16 gated residual (read-modify-write Cb).
template<int ACT, int OUT, int TN, int TM>
__global__ __launch_bounds__(256) void gemm_lds(
    const unsigned short* __restrict__ A,
    const unsigned short* __restrict__ BT,
    const float* __restrict__ bias,
    float* __restrict__ Cf, unsigned short* __restrict__ Cb, int ldc,
    int K, int qscale_cols,
    const float* __restrict__ mod, int modstride, int gchunk, int ntok, int mrows,
    size_t bt_zs = 0, size_t bias_zs = 0, size_t c_zs = 0)
{
    constexpr int NCF = TN / 32;       // col frags per wave
    constexpr int NBS = TN / 64;       // B stage issues per thread
    constexpr int NMR = TM / 32;       // row frags per wave
    constexpr int NAI = TM / 64;       // A stage issues per thread
    constexpr int NST = (NAI > NBS) ? NAI : NBS;   // staging addr table size
    if (bt_zs) BT += (size_t)blockIdx.z * bt_zs;
    if (bias && bias_zs) bias += (size_t)blockIdx.z * bias_zs;
    if (c_zs) { if (Cf) Cf += (size_t)blockIdx.z * c_zs; if (Cb) Cb += (size_t)blockIdx.z * c_zs; }
    __shared__ unsigned short As[2][TM * 32];
    __shared__ unsigned short Bs[2][TN * 32];
    int tid = threadIdx.x, w = tid >> 6, lane = tid & 63;
    int row0 = blockIdx.y * TM, col0 = blockIdx.x * TN;
    int wrow = (w >> 1) * (TM / 2), wcol = (w & 1) * (TN / 2);
    int lr = lane & 15, g = lane >> 4;
    f32x4 acc[NMR][NCF] = {};

    int ra[NST], ka[NST], la[NST];
    #pragma unroll
    for (int i = 0; i < NST; ++i) {
        int off = tid * 16 + i * 4096;
        int row = off >> 6;
        int slot = (off >> 4) & 3;
        ra[i] = row;
        ka[i] = (slot ^ ((row >> 1) & 3)) * 8;
        la[i] = off >> 1;
    }
    int nt = K >> 5, cur = 0;
    #pragma unroll
    for (int i = 0; i < NAI; ++i)
        gl16(A + (size_t)(row0 + ra[i]) * K + ka[i], &As[0][la[i]]);
    #pragma unroll
    for (int i = 0; i < NBS; ++i)
        gl16(BT + (size_t)(col0 + ra[i]) * K + ka[i], &Bs[0][la[i]]);

    for (int t = 0; t < nt; ++t) {
        __syncthreads();
        if (t + 1 < nt) {
            int k0 = (t + 1) << 5;
            #pragma unroll
            for (int i = 0; i < NAI; ++i)
                gl16(A + (size_t)(row0 + ra[i]) * K + k0 + ka[i], &As[cur ^ 1][la[i]]);
            #pragma unroll
            for (int i = 0; i < NBS; ++i)
                gl16(BT + (size_t)(col0 + ra[i]) * K + k0 + ka[i], &Bs[cur ^ 1][la[i]]);
        }
        short8v av[NMR], bv[NCF];
        #pragma unroll
        for (int mr = 0; mr < NMR; ++mr) {
            int row = wrow + mr * 16 + lr;
            av[mr] = *(const short8v*)&As[cur][row * 32 + (g ^ ((row >> 1) & 3)) * 8];
        }
        #pragma unroll
        for (int nc = 0; nc < NCF; ++nc) {
            int row = wcol + nc * 16 + lr;
            bv[nc] = *(const short8v*)&Bs[cur][row * 32 + (g ^ ((row >> 1) & 3)) * 8];
        }
        #pragma unroll
        for (int mr = 0; mr < NMR; ++mr)
            #pragma unroll
            for (int nc = 0; nc < NCF; ++nc)
                acc[mr][nc] = __builtin_amdgcn_mfma_f32_16x16x32_bf16(
                    av[mr], bv[nc], acc[mr][nc], 0, 0, 0);
        cur ^= 1;
    }
    int rbase = g * 4;
    #pragma unroll
    for (int mr = 0; mr < NMR; ++mr) {
        #pragma unroll
        for (int nc = 0; nc < NCF; ++nc) {
            int gc = col0 + wcol + nc * 16 + lr;
            float bb = bias ? bias[gc] : 0.f;
            #pragma unroll
            for (int r = 0; r < 4; ++r) {
                int gr = row0 + wrow + mr * 16 + rbase + r;
                if (gr >= mrows) continue;
                float v = acc[mr][nc][r] + bb;
                if (ACT == 1) v = siluf(v);
                if (ACT == 2) v = geluf(v);
                if (OUT == 0) {
                    Cf[(size_t)gr * ldc + gc] = v;
                } else if (OUT == 1) {
                    if (gc < qscale_cols) v *= 0.125f;
                    Cb[(size_t)gr * ldc + gc] = f2bf(v);
                } else {
                    float gg = 1.f;
                    if (mod) gg = mod[(size_t)(gr / ntok) * modstride + gchunk * D + gc];
                    size_t idx = (size_t)gr * ldc + gc;
                    Cb[idx] = f2bf(bf2f(Cb[idx]) + gg * v);
                }
            }
        }
    }
}

// ---------------- MFMA GEMM: TM=256 x TN=128, 8 waves, 512 threads ----------
template<int ACT>
__global__ __launch_bounds__(512, 4) void gemm_lds256(
    const unsigned short* __restrict__ A,
    const unsigned short* __restrict__ BT,
    const float* __restrict__ bias,
    unsigned short* __restrict__ Cb, int ldc,
    int K, int qscale_cols)
{
    __shared__ unsigned short As[2][256 * 32];
    __shared__ unsigned short Bs[2][128 * 32];
    int tid = threadIdx.x, w = tid >> 6, lane = tid & 63;
    int row0 = blockIdx.y * 256, col0 = blockIdx.x * 128;
    int wrow = (w >> 1) * 64, wcol = (w & 1) * 64;
    int lr = lane & 15, g = lane >> 4;
    f32x4 acc[4][4] = {};

    int ra[2], ka[2], la[2];
    #pragma unroll
    for (int i = 0; i < 2; ++i) {
        int off = tid * 16 + i * 8192;
        int row = off >> 6;
        int slot = (off >> 4) & 3;
        ra[i] = row;
        ka[i] = (slot ^ ((row >> 1) & 3)) * 8;
        la[i] = off >> 1;
    }
    int rb, kb, lb;
    {
        int off = tid * 16;
        int row = off >> 6;
        int slot = (off >> 4) & 3;
        rb = row;
        kb = (slot ^ ((row >> 1) & 3)) * 8;
        lb = off >> 1;
    }
    int nt = K >> 5, cur = 0;
    #pragma unroll
    for (int i = 0; i < 2; ++i)
        gl16(A + (size_t)(row0 + ra[i]) * K + ka[i], &As[0][la[i]]);
    gl16(BT + (size_t)(col0 + rb) * K + kb, &Bs[0][lb]);

    for (int t = 0; t < nt; ++t) {
        __syncthreads();
        if (t + 1 < nt) {
            int k0 = (t + 1) << 5;
            #pragma unroll
            for (int i = 0; i < 2; ++i)
                gl16(A + (size_t)(row0 + ra[i]) * K + k0 + ka[i], &As[cur ^ 1][la[i]]);
            gl16(BT + (size_t)(col0 + rb) * K + k0 + kb, &Bs[cur ^ 1][lb]);
        }
        short8v av[4], bv[4];
        #pragma unroll
        for (int mr = 0; mr < 4; ++mr) {
            int row = wrow + mr * 16 + lr;
            av[mr] = *(const short8v*)&As[cur][row * 32 + (g ^ ((row >> 1) & 3)) * 8];
        }
        #pragma unroll
        for (int nc = 0; nc < 4; ++nc) {
            int row = wcol + nc * 16 + lr;
            bv[nc] = *(const short8v*)&Bs[cur][row * 32 + (g ^ ((row >> 1) & 3)) * 8];
        }
        #pragma unroll
        for (int mr = 0; mr < 4; ++mr)
            #pragma unroll
            for (int nc = 0; nc < 4; ++nc)
                acc[mr][nc] = __builtin_amdgcn_mfma_f32_16x16x32_bf16(
                    av[mr], bv[nc], acc[mr][nc], 0, 0, 0);
        cur ^= 1;
    }
    int rbase = g * 4;
    #pragma unroll
    for (int mr = 0; mr < 4; ++mr) {
        #pragma unroll
        for (int nc = 0; nc < 4; ++nc) {
            int gc = col0 + wcol + nc * 16 + lr;
            float bb = bias ? bias[gc] : 0.f;
            #pragma unroll
            for (int r = 0; r < 4; ++r) {
                int gr = row0 + wrow + mr * 16 + rbase + r;
                float v = acc[mr][nc][r] + bb;
                if (ACT == 2) v = geluf(v);
                if (gc < qscale_cols) v *= 0.125f;
                Cb[(size_t)gr * ldc + gc] = f2bf(v);
            }
        }
    }
}

// ---------------- MoE gathered MFMA GEMM ----------
template<int PHASE>
__global__ __launch_bounds__(256) void moe_lds(
    const unsigned short* __restrict__ A,
    const unsigned short* __restrict__ BTconv,
    unsigned short* __restrict__ Cb,
    const int* __restrict__ cnt, const int* __restrict__ list,
    const float* __restrict__ gval, int RT, int egbase)
{
    constexpr int K  = (PHASE == 1) ? 768 : 3072;
    constexpr int TN = (PHASE == 1) ? 128 : 64;
    constexpr int NCF = TN / 32;
    constexpr int NBS = TN / 64;
    int egl = blockIdx.y / RT, rt = blockIdx.y % RT;
    int eg = egbase + egl;
    int c0 = cnt[eg];
    int mbase = rt * 128;
    if (mbase >= c0) return;
    int mcount = min(128, c0 - mbase);
    __shared__ int toks[128];
    int tid = threadIdx.x, w = tid >> 6, lane = tid & 63;
    if (tid < 128) toks[tid] = list[eg * MAXTOK + mbase + min(tid, mcount - 1)];
    __syncthreads();

    __shared__ unsigned short As[2][128 * 32];
    __shared__ unsigned short Bs[2][TN * 32];
    const unsigned short* BT = BTconv + (size_t)egl * (768 * 3072);
    int col0 = blockIdx.x * TN;
    int wrow = (w >> 1) * 64, wcol = (w & 1) * (TN / 2);
    int lr = lane & 15, g = lane >> 4;
    f32x4 acc[4][NCF] = {};

    int ra[2], ka[2], la[2], tok_s[2];
    #pragma unroll
    for (int i = 0; i < 2; ++i) {
        int off = tid * 16 + i * 4096;
        int row = off >> 6;
        int slot = (off >> 4) & 3;
        ra[i] = row;
        ka[i] = (slot ^ ((row >> 1) & 3)) * 8;
        la[i] = off >> 1;
        tok_s[i] = toks[row];
    }
    int nt = K >> 5, cur = 0;
    #pragma unroll
    for (int i = 0; i < 2; ++i)
        gl16(A + (size_t)tok_s[i] * K + ka[i], &As[0][la[i]]);
    #pragma unroll
    for (int i = 0; i < NBS; ++i)
        gl16(BT + (size_t)(col0 + ra[i]) * K + ka[i], &Bs[0][la[i]]);

    for (int t = 0; t < nt; ++t) {
        __syncthreads();
        if (t + 1 < nt) {
            int k0 = (t + 1) << 5;
            #pragma unroll
            for (int i = 0; i < 2; ++i)
                gl16(A + (size_t)tok_s[i] * K + k0 + ka[i], &As[cur ^ 1][la[i]]);
            #pragma unroll
            for (int i = 0; i < NBS; ++i)
                gl16(BT + (size_t)(col0 + ra[i]) * K + k0 + ka[i], &Bs[cur ^ 1][la[i]]);
        }
        short8v av[4], bv[NCF];
        #pragma unroll
        for (int mr = 0; mr < 4; ++mr) {
            int row = wrow + mr * 16 + lr;
            av[mr] = *(const short8v*)&As[cur][row * 32 + (g ^ ((row >> 1) & 3)) * 8];
        }
        #pragma unroll
        for (int nc = 0; nc < NCF; ++nc) {
            int row = wcol + nc * 16 + lr;
            bv[nc] = *(const short8v*)&Bs[cur][row * 32 + (g ^ ((row >> 1) & 3)) * 8];
        }
        #pragma unroll
        for (int mr = 0; mr < 4; ++mr)
            #pragma unroll
            for (int nc = 0; nc < NCF; ++nc)
                acc[mr][nc] = __builtin_amdgcn_mfma_f32_16x16x32_bf16(
                    av[mr], bv[nc], acc[mr][nc], 0, 0, 0);
        cur ^= 1;
    }
    int rbase = g * 4;
    #pragma unroll
    for (int mr = 0; mr < 4; ++mr) {
        #pragma unroll
        for (int r = 0; r < 4; ++r) {
            int m = wrow + mr * 16 + rbase + r;
            if (m >= mcount) continue;
            int tok = toks[m];
            #pragma unroll
            for (int nc = 0; nc < NCF; ++nc) {
                int gc = col0 + wcol + nc * 16 + lr;
                float v = acc[mr][nc][r];
                if (PHASE == 1) Cb[(size_t)tok * 3072 + gc] = f2bf(geluf(v));
                else {
                    size_t idx = (size_t)tok * 768 + gc;
                    Cb[idx] = f2bf(bf2f(Cb[idx]) + gval[tok] * v);
                }
            }
        }
    }
}

// ---------------- MoE phase-2 with split-K (4 segments of 768) ----------
__global__ __launch_bounds__(256) void moe_lds2k(
    const unsigned short* __restrict__ A,       // hbuf [tok][3072]
    const unsigned short* __restrict__ BTconv,  // [egl][768][3072]
    float* __restrict__ scr,                    // [tok][768] f32 partials
    const int* __restrict__ cnt, const int* __restrict__ list, int RT)
{
    constexpr int K = 3072;
    constexpr int TN = 64;
    constexpr int NCF = 2;
    int egl = blockIdx.y / RT, rt = blockIdx.y % RT;
    int c0 = cnt[egl];
    int mbase = rt * 128;
    if (mbase >= c0) return;
    int mcount = min(128, c0 - mbase);
    __shared__ int toks[128];
    int tid = threadIdx.x, w = tid >> 6, lane = tid & 63;
    if (tid < 128) toks[tid] = list[egl * MAXTOK + mbase + min(tid, mcount - 1)];
    __syncthreads();

    __shared__ unsigned short As[2][128 * 32];
    __shared__ unsigned short Bs[2][TN * 32];
    const unsigned short* BT = BTconv + (size_t)egl * (768 * 3072);
    int col0 = blockIdx.x * TN;
    int ksbase = blockIdx.z * 768;              // K segment
    int wrow = (w >> 1) * 64, wcol = (w & 1) * (TN / 2);
    int lr = lane & 15, g = lane >> 4;
    f32x4 acc[4][NCF] = {};

    int ra[2], ka[2], la[2], tok_s[2];
    #pragma unroll
    for (int i = 0; i < 2; ++i) {
        int off = tid * 16 + i * 4096;
        int row = off >> 6;
        int slot = (off >> 4) & 3;
        ra[i] = row;
        ka[i] = (slot ^ ((row >> 1) & 3)) * 8;
        la[i] = off >> 1;
        tok_s[i] = toks[row];
    }
    int nt = 768 >> 5, cur = 0;
    #pragma unroll
    for (int i = 0; i < 2; ++i)
        gl16(A + (size_t)tok_s[i] * K + ksbase + ka[i], &As[0][la[i]]);
    gl16(BT + (size_t)(col0 + ra[0]) * K + ksbase + ka[0], &Bs[0][la[0]]);

    for (int t = 0; t < nt; ++t) {
        __syncthreads();
        if (t + 1 < nt) {
            int k0 = ksbase + ((t + 1) << 5);
            #pragma unroll
            for (int i = 0; i < 2; ++i)
                gl16(A + (size_t)tok_s[i] * K + k0 + ka[i], &As[cur ^ 1][la[i]]);
            gl16(BT + (size_t)(col0 + ra[0]) * K + k0 + ka[0], &Bs[cur ^ 1][la[0]]);
        }
        short8v av[4], bv[NCF];
        #pragma unroll
        for (int mr = 0; mr < 4; ++mr) {
            int row = wrow + mr * 16 + lr;
            av[mr] = *(const short8v*)&As[cur][row * 32 + (g ^ ((row >> 1) & 3)) * 8];
        }
        #pragma unroll
        for (int nc = 0; nc < NCF; ++nc) {
            int row = wcol + nc * 16 + lr;
            bv[nc] = *(const short8v*)&Bs[cur][row * 32 + (g ^ ((row >> 1) & 3)) * 8];
        }
        #pragma unroll
        for (int mr = 0; mr < 4; ++mr)
            #pragma unroll
            for (int nc = 0; nc < NCF; ++nc)
                acc[mr][nc] = __builtin_amdgcn_mfma_f32_16x16x32_bf16(
                    av[mr], bv[nc], acc[mr][nc], 0, 0, 0);
        cur ^= 1;
    }
    int rbase = g * 4;
    #pragma unroll
    for (int mr = 0; mr < 4; ++mr) {
        #pragma unroll
        for (int r = 0; r < 4; ++r) {
            int m = wrow + mr * 16 + rbase + r;
            if (m >= mcount) continue;
            int tok = toks[m];
            #pragma unroll
            for (int nc = 0; nc < NCF; ++nc) {
                int gc = col0 + wcol + nc * 16 + lr;
                atomicAdd(&scr[(size_t)tok * 768 + gc], acc[mr][nc][r]);
            }
        }
    }
}

// ---------------- LayerNorm (bf16 in) -> bf16 ----------------
__global__ __launch_bounds__(256) void ln_kernel(
    const unsigned short* __restrict__ X, unsigned short* __restrict__ Y, int R, int ntok,
    const float* __restrict__ mod, int modstride, int shift_chunk, int scale_chunk)
{
    int r = blockIdx.x;
    if (r >= R) return;
    const unsigned short* xr = X + (size_t)r * D;
    int tid = threadIdx.x;
    int lane = tid & 63, wid = tid >> 6;
    float v0 = bf2f(xr[tid]), v1 = bf2f(xr[tid + 256]), v2 = bf2f(xr[tid + 512]);
    float s = v0 + v1 + v2;
    float s2 = v0 * v0 + v1 * v1 + v2 * v2;
    for (int off = 32; off > 0; off >>= 1) {
        s += __shfl_xor(s, off, 64);
        s2 += __shfl_xor(s2, off, 64);
    }
    __shared__ float shs[4], shs2[4];
    if (lane == 0) { shs[wid] = s; shs2[wid] = s2; }
    __syncthreads();
    float tot = shs[0] + shs[1] + shs[2] + shs[3];
    float tot2 = shs2[0] + shs2[1] + shs2[2] + shs2[3];
    float mu = tot * (1.f / 768.f);
    float var = tot2 * (1.f / 768.f) - mu * mu;
    float rs = rsqrtf(var + 1e-6f);
    int bb = r / ntok;
    float vv[3] = {v0, v1, v2};
    #pragma unroll
    for (int j = 0; j < 3; ++j) {
        int col = tid + j * 256;
        float nrm = (vv[j] - mu) * rs;
        float y = nrm;
        if (mod) {
            float scv = mod[(size_t)bb * modstride + scale_chunk * D + col];
            float shv = mod[(size_t)bb * modstride + shift_chunk * D + col];
            y = nrm * (1.f + scv) + shv;
        }
        Y[(size_t)r * D + col] = f2bf(y);
    }
}

// ---------------- MFMA flash attention (V transposed in-kernel) ----------
__global__ __launch_bounds__(512) void attn_mfma(
    const unsigned short* __restrict__ Qp, int ldq, int qoff,
    const unsigned short* __restrict__ Kp, int ldk, int koff,
    const unsigned short* __restrict__ Vp, int ldv, int voff,
    unsigned short* __restrict__ O, int ldo,
    int Nq, int Nkv)
{
    __shared__ unsigned short Qs[128 * 64];
    __shared__ unsigned short Ks[64 * 64];
    __shared__ unsigned short Vs[64 * 64];
    __shared__ unsigned short Ps[128 * 64];
    int h = blockIdx.y, b = blockIdx.z, q0 = blockIdx.x * 128;
    int tid = threadIdx.x, w = tid >> 6, lane = tid & 63;
    int wrow = w * 16;
    int lr = lane & 15, g = lane >> 4;

    {
        int srow = tid >> 2, sc = (tid & 3) * 16;
        int gr = min(q0 + srow, Nq - 1);
        const unsigned short* qp = Qp + (size_t)(b * Nq + gr) * ldq + qoff + h * 64 + sc;
        short8v v0 = *(const short8v*)qp, v1 = *(const short8v*)(qp + 8);
        int s0 = sc >> 3;
        *(short8v*)&Qs[srow * 64 + (s0 ^ (srow & 7)) * 8] = v0;
        *(short8v*)&Qs[srow * 64 + ((s0 + 1) ^ (srow & 7)) * 8] = v1;
    }
    float m_r[4] = {-1e30f, -1e30f, -1e30f, -1e30f};
    float l_r[4] = {};
    f32x4 acc0 = {}, acc1 = {}, acc2 = {}, acc3 = {};

    for (int kv0 = 0; kv0 < Nkv; kv0 += 64) {
        {
            int t2 = tid & 255;
            int srow = t2 >> 2, sc = (t2 & 3) * 16;
            int gc = min(kv0 + srow, Nkv - 1);
            if (tid < 256) {
                const unsigned short* kp = Kp + (size_t)(b * Nkv + gc) * ldk + koff + h * 64 + sc;
                short8v v0 = *(const short8v*)kp, v1 = *(const short8v*)(kp + 8);
                int s0 = sc >> 3;
                *(short8v*)&Ks[srow * 64 + (s0 ^ (srow & 7)) * 8] = v0;
                *(short8v*)&Ks[srow * 64 + ((s0 + 1) ^ (srow & 7)) * 8] = v1;
            } else {
                const unsigned short* vp = Vp + (size_t)(b * Nkv + gc) * ldv + voff + h * 64 + sc;
                #pragma unroll
                for (int j = 0; j < 16; ++j) {
                    int d = sc + j;
                    Vs[d * 64 + (((srow >> 3) ^ (d & 7)) * 8) + (srow & 7)] = vp[j];
                }
            }
        }
        __syncthreads();
        short8v aq0, aq1;
        {
            int row = wrow + lr;
            aq0 = *(const short8v*)&Qs[row * 64 + ((0 + g) ^ (row & 7)) * 8];
            aq1 = *(const short8v*)&Qs[row * 64 + ((4 + g) ^ (row & 7)) * 8];
        }
        f32x4 sf[4];
        #pragma unroll
        for (int nc = 0; nc < 4; ++nc) {
            int row = nc * 16 + lr;
            short8v bk0 = *(const short8v*)&Ks[row * 64 + ((0 + g) ^ (row & 7)) * 8];
            short8v bk1 = *(const short8v*)&Ks[row * 64 + ((4 + g) ^ (row & 7)) * 8];
            f32x4 z = {};
            z = __builtin_amdgcn_mfma_f32_16x16x32_bf16(aq0, bk0, z, 0, 0, 0);
            sf[nc] = __builtin_amdgcn_mfma_f32_16x16x32_bf16(aq1, bk1, z, 0, 0, 0);
        }
        bool val0 = (kv0 + 0 * 16 + lr) < Nkv;
        bool val1 = (kv0 + 1 * 16 + lr) < Nkv;
        bool val2 = (kv0 + 2 * 16 + lr) < Nkv;
        bool val3 = (kv0 + 3 * 16 + lr) < Nkv;
        float fs[4];
        #pragma unroll
        for (int r = 0; r < 4; ++r) {
            float s0 = val0 ? sf[0][r] : -1e30f;
            float s1 = val1 ? sf[1][r] : -1e30f;
            float s2 = val2 ? sf[2][r] : -1e30f;
            float s3 = val3 ? sf[3][r] : -1e30f;
            float mx = fmaxf(fmaxf(s0, s1), fmaxf(s2, s3));
            mx = fmaxf(mx, __shfl_xor(mx, 1, 64));
            mx = fmaxf(mx, __shfl_xor(mx, 2, 64));
            mx = fmaxf(mx, __shfl_xor(mx, 4, 64));
            mx = fmaxf(mx, __shfl_xor(mx, 8, 64));
            float mn = fmaxf(m_r[r], mx);
            fs[r] = __expf(m_r[r] - mn);
            m_r[r] = mn;
            float p0 = __expf(s0 - mn), p1 = __expf(s1 - mn);
            float p2 = __expf(s2 - mn), p3 = __expf(s3 - mn);
            float rsum = p0 + p1 + p2 + p3;
            rsum += __shfl_xor(rsum, 1, 64);
            rsum += __shfl_xor(rsum, 2, 64);
            rsum += __shfl_xor(rsum, 4, 64);
            rsum += __shfl_xor(rsum, 8, 64);
            l_r[r] = l_r[r] * fs[r] + rsum;
            int ql = wrow + g * 4 + r;
            int base = ql * 64;
            int x7 = ql & 7;
            Ps[base + (((0 * 16 + lr) >> 3) ^ x7) * 8 + (lr & 7)] = f2bf(p0);
            Ps[base + (((1 * 16 + lr) >> 3) ^ x7) * 8 + (lr & 7)] = f2bf(p1);
            Ps[base + (((2 * 16 + lr) >> 3) ^ x7) * 8 + (lr & 7)] = f2bf(p2);
            Ps[base + (((3 * 16 + lr) >> 3) ^ x7) * 8 + (lr & 7)] = f2bf(p3);
            acc0[r] *= fs[r]; acc1[r] *= fs[r]; acc2[r] *= fs[r]; acc3[r] *= fs[r];
        }
        __syncthreads();
        short8v ap0, ap1;
        {
            int row = wrow + lr;
            ap0 = *(const short8v*)&Ps[row * 64 + ((0 + g) ^ (row & 7)) * 8];
            ap1 = *(const short8v*)&Ps[row * 64 + ((4 + g) ^ (row & 7)) * 8];
        }
        {
            int row = 0 * 16 + lr;
            short8v b0 = *(const short8v*)&Vs[row * 64 + ((0 + g) ^ (row & 7)) * 8];
            short8v b1 = *(const short8v*)&Vs[row * 64 + ((4 + g) ^ (row & 7)) * 8];
            acc0 = __builtin_amdgcn_mfma_f32_16x16x32_bf16(ap0, b0, acc0, 0, 0, 0);
            acc0 = __builtin_amdgcn_mfma_f32_16x16x32_bf16(ap1, b1, acc0, 0, 0, 0);
        }
        {
            int row = 1 * 16 + lr;
            short8v b0 = *(const short8v*)&Vs[row * 64 + ((0 + g) ^ (row & 7)) * 8];
            short8v b1 = *(const short8v*)&Vs[row * 64 + ((4 + g) ^ (row & 7)) * 8];
            acc1 = __builtin_amdgcn_mfma_f32_16x16x32_bf16(ap0, b0, acc1, 0, 0, 0);
            acc1 = __builtin_amdgcn_mfma_f32_16x16x32_bf16(ap1, b1, acc1, 0, 0, 0);
        }
        {
            int row = 2 * 16 + lr;
            short8v b0 = *(const short8v*)&Vs[row * 64 + ((0 + g) ^ (row & 7)) * 8];
            short8v b1 = *(const short8v*)&Vs[row * 64 + ((4 + g) ^ (row & 7)) * 8];
            acc2 = __builtin_amdgcn_mfma_f32_16x16x32_bf16(ap0, b0, acc2, 0, 0, 0);
            acc2 = __builtin_amdgcn_mfma_f32_16x16x32_bf16(ap1, b1, acc2, 0, 0, 0);
        }
        {
            int row = 3 * 16 + lr;
            short8v b0 = *(const short8v*)&Vs[row * 64 + ((0 + g) ^ (row & 7)) * 8];
            short8v b1 = *(const short8v*)&Vs[row * 64 + ((4 + g) ^ (row & 7)) * 8];
            acc3 = __builtin_amdgcn_mfma_f32_16x16x32_bf16(ap0, b0, acc3, 0, 0, 0);
            acc3 = __builtin_amdgcn_mfma_f32_16x16x32_bf16(ap1, b1, acc3, 0, 0, 0);
        }
        __syncthreads();
    }
    #pragma unroll
    for (int r = 0; r < 4; ++r) {
        int ql = wrow + g * 4 + r;
        if (q0 + ql >= Nq) continue;
        float rl = 1.f / l_r[r];
        unsigned short* op = O + (size_t)(b * Nq + q0 + ql) * ldo + h * 64 + lr;
        op[0]  = f2bf(acc0[r] * rl);
        op[16] = f2bf(acc1[r] * rl);
        op[32] = f2bf(acc2[r] * rl);
        op[48] = f2bf(acc3[r] * rl);
    }
}

// ---------------- MoE router ----------------
__global__ __launch_bounds__(64) void router_kernel(
    const unsigned short* __restrict__ X, const float* __restrict__ WrBase,
    int* __restrict__ idx, float* __restrict__ gval)
{
    int tkn = blockIdx.x; int lane = threadIdx.x;
    int grp = (tkn >= 768) ? 2 : (tkn >= 512 ? 1 : 0);
    const float* Wr = WrBase + (size_t)grp * D * NEXP;
    const unsigned short* xr = X + (size_t)tkn * D;
    float p0 = 0, p1 = 0, p2 = 0, p3 = 0;
    for (int dd = lane; dd < D; dd += 64) {
        float xv = bf2f(xr[dd]);
        const float* wq = Wr + dd * 4;
        p0 += xv * wq[0]; p1 += xv * wq[1]; p2 += xv * wq[2]; p3 += xv * wq[3];
    }
    for (int off = 32; off > 0; off >>= 1) {
        p0 += __shfl_xor(p0, off, 64); p1 += __shfl_xor(p1, off, 64);
        p2 += __shfl_xor(p2, off, 64); p3 += __shfl_xor(p3, off, 64);
    }
    if (lane == 0) {
        float best = p0; int e = 0;
        if (p1 > best) { best = p1; e = 1; }
        if (p2 > best) { best = p2; e = 2; }
        if (p3 > best) { best = p3; e = 3; }
        float sum = expf(p0 - best) + expf(p1 - best) + expf(p2 - best) + expf(p3 - best);
        idx[tkn] = grp * 4 + e;
        gval[tkn] = 1.f / sum;
    }
}

__global__ __launch_bounds__(256) void scatter_kernel(
    const int* __restrict__ idx, int* __restrict__ cnt,
    int* __restrict__ list, int ntok)
{
    __shared__ int lcnt[12];
    int tid = threadIdx.x;
    if (tid < 12) lcnt[tid] = 0;
    __syncthreads();
    for (int i = tid; i < ntok; i += 256) {
        int e = idx[i];
        int pos = atomicAdd(&lcnt[e], 1);
        list[e * MAXTOK + pos] = i;
    }
    __syncthreads();
    if (tid < 12) cnt[tid] = lcnt[tid];
}

// ---------------- concat (traj f32 + groups bf16 -> x bf16) ----------------
__global__ void concat_kernel(const float* __restrict__ traj, const unsigned short* __restrict__ a,
                              const unsigned short* __restrict__ bg, const unsigned short* __restrict__ cg,
                              unsigned short* __restrict__ x, int total)
{
    int i = blockIdx.x * blockDim.x + threadIdx.x;
    if (i >= total) return;
    int col = i % D;
    int r = i / D;
    int n = r % NTOK, b = r / NTOK;
    unsigned short v;
    if (n < 256)      v = f2bf(traj[((size_t)b * 256 + n) * D + col]);
    else if (n < 320) v = a[((size_t)b * 64 + (n - 256)) * D + col];
    else if (n < 352) v = bg[((size_t)b * 32 + (n - 320)) * D + col];
    else              v = cg[((size_t)b * 192 + (n - 352)) * D + col];
    x[i] = v;
}

// ---------------- output head ----------------
__global__ void head_prep(const float* __restrict__ W, unsigned short* __restrict__ WT14) {
    int i = blockIdx.x * blockDim.x + threadIdx.x;
    if (i >= 14 * 768) return;
    int o = i / 768, d = i % 768;
    WT14[i] = f2bf(W[d * 14 + o]);
}

__global__ __launch_bounds__(64) void head_kernel(
    const unsigned short* __restrict__ lnb, const unsigned short* __restrict__ WT14,
    const float* __restrict__ bias, float* __restrict__ out)
{
    int r = blockIdx.x;
    int b = r >> 8, n = r & 255;
    const unsigned short* hrow = lnb + (size_t)(b * NTOK + n) * D;
    int l = threadIdx.x;
    if (l >= 56) return;
    int o = l >> 2, p = l & 3;
    const unsigned short* hp = hrow + p * 192;
    const unsigned short* wp = WT14 + o * 768 + p * 192;
    float acc = 0.f;
    for (int i = 0; i < 192; i += 8) {
        short8v hv = *(const short8v*)(hp + i);
        short8v wv = *(const short8v*)(wp + i);
        #pragma unroll
        for (int j = 0; j < 8; ++j)
            acc += bf2f((unsigned short)hv[j]) * bf2f((unsigned short)wv[j]);
    }
    acc += __shfl_xor(acc, 1, 64);
    acc += __shfl_xor(acc, 2, 64);
    if (p == 0) out[(size_t)r * 14 + o] = acc + bias[o];
}

// ---------------- host helpers ----------------
static inline void tcvt(const float* W, unsigned short* WT, int K, int N, int z, hipStream_t s) {
    transpose_cvt<<<dim3(N / 64, K / 64, z), 256, 0, s>>>(W, WT, K, N);
}
// gemm_lds256 for big-N GEMMs (qkv/mlp1): TM=256 amortizes B-panel re-reads
// (round-20 lesson: TM=64 there quadruples B traffic past L2 -> regression).
static inline void g_bf(int act, const unsigned short* A, const unsigned short* BT,
                        const float* bias, unsigned short* C, int ldc,
                        int M, int N, int K, int qcols, hipStream_t s)
{
    if (M % 256 == 0 && N % 128 == 0 && N >= 2304) {
        dim3 g(N / 128, M / 256);
        if (act == 2) gemm_lds256<2><<<g, 512, 0, s>>>(A, BT, bias, C, ldc, K, qcols);
        else          gemm_lds256<0><<<g, 512, 0, s>>>(A, BT, bias, C, ldc, K, qcols);
        return;
    }
    bool small = (M <= 1536);   // cross-attn GEMMs: TM=64 for grid occupancy
    if (N != 768) {
        if (small) {
            dim3 g(N / 128, M / 64);
            if (act == 2) gemm_lds<2, 1, 128, 64><<<g, 256, 0, s>>>(A, BT, bias, nullptr, C, ldc, K, qcols, nullptr, 0, 0, 1, 1 << 30);
            else          gemm_lds<0, 1, 128, 64><<<g, 256, 0, s>>>(A, BT, bias, nullptr, C, ldc, K, qcols, nullptr, 0, 0, 1, 1 << 30);
        } else {
            dim3 g(N / 128, M / 128);
            if (act == 2) gemm_lds<2, 1, 128, 128><<<g, 256, 0, s>>>(A, BT, bias, nullptr, C, ldc, K, qcols, nullptr, 0, 0, 1, 1 << 30);
            else          gemm_lds<0, 1, 128, 128><<<g, 256, 0, s>>>(A, BT, bias, nullptr, C, ldc, K, qcols, nullptr, 0, 0, 1, 1 << 30);
        }
    } else {
        if (small) {
            dim3 g(N / 64, M / 64);
            if (act == 2) gemm_lds<2, 1, 64, 64><<<g, 256, 0, s>>>(A, BT, bias, nullptr, C, ldc, K, qcols, nullptr, 0, 0, 1, 1 << 30);
            else          gemm_lds<0, 1, 64, 64><<<g, 256, 0, s>>>(A, BT, bias, nullptr, C, ldc, K, qcols, nullptr, 0, 0, 1, 1 << 30);
        } else {
            dim3 g(N / 64, M / 128);
            if (act == 2) gemm_lds<2, 1, 64, 128><<<g, 256, 0, s>>>(A, BT, bias, nullptr, C, ldc, K, qcols, nullptr, 0, 0, 1, 1 << 30);
            else          gemm_lds<0, 1, 64, 128><<<g, 256, 0, s>>>(A, BT, bias, nullptr, C, ldc, K, qcols, nullptr, 0, 0, 1, 1 << 30);
        }
    }
}
// g_res: TM=64 everywhere (round-19 win; N=768 B-panels stay L2-resident).
static inline void g_res(const unsigned short* A, const unsigned short* BT,
                         const float* bias, unsigned short* C, int ldc, int M, int N, int K,
                         const float* mod, int modstride, int gchunk, int ntok, hipStream_t s)
{
    dim3 g(N / 64, M / 64);
    gemm_lds<0, 2, 64, 64><<<g, 256, 0, s>>>(A, BT, bias, nullptr, C, ldc, K, 0, mod, modstride, gchunk, ntok, 1 << 30);
}

extern "C" void kernel_launch(void* const* d_in, const int* in_sizes, int n_in,
                              void* d_out, int out_size, void* d_ws, size_t ws_size,
                              hipStream_t stream)
{
    const float* x_traj   = (const float*)d_in[0];
    const int*   t_arr    = (const int*)d_in[1];
    const float* tokA     = (const float*)d_in[2];
    const float* tokB     = (const float*)d_in[3];
    const float* tokC     = (const float*)d_in[4];
    const float* W_traj   = (const float*)d_in[5];
    const float* b_traj   = (const float*)d_in[6];
    const float* W_ftime  = (const float*)d_in[7];
    const float* Wt1      = (const float*)d_in[8];
    const float* bt1      = (const float*)d_in[9];
    const float* Wt2      = (const float*)d_in[10];
    const float* bt2      = (const float*)d_in[11];
    const float* moe_attn = (const float*)d_in[12];
    const float* moe_rout = (const float*)d_in[13];
    const float* moe_W1   = (const float*)d_in[14];
    const float* moe_W2   = (const float*)d_in[15];
    const float* dit_qkv  = (const float*)d_in[16];
    const float* dit_qkvb = (const float*)d_in[17];
    const float* dit_proj = (const float*)d_in[18];
    const float* dit_projb= (const float*)d_in[19];
    const float* dit_mlp1 = (const float*)d_in[20];
    const float* dit_mlp1b= (const float*)d_in[21];
    const float* dit_mlp2 = (const float*)d_in[22];
    const float* dit_mlp2b= (const float*)d_in[23];
    const float* dit_ada  = (const float*)d_in[24];
    const float* dit_adab = (const float*)d_in[25];
    const float* out_adaW = (const float*)d_in[26];
    const float* out_adab = (const float*)d_in[27];
    const float* out_W    = (const float*)d_in[28];
    const float* out_b    = (const float*)d_in[29];
    float* out = (float*)d_out;
    float* ws = (float*)d_ws;

    const size_t o_cnt  = 14336;
    const size_t o_idx  = 14400;
    const size_t o_gval = 16704;
    const size_t o_list = 19008;
    const size_t o_traj = 66624;             // f32 traj; later mod buffers
    const size_t o_a    = 1639488;           // bf16 a|bg|cg = 2304x768 shorts
    const size_t o_x    = 3408960;           // bf16 x
    const size_t o_lnb  = 6751296;
    const size_t o_qkvb = 8422464;
    const size_t o_attnO= 13435968;
    const size_t o_h    = 15107136;
    const size_t o_wt   = 24151104;
    const size_t o_wt14 = 28869696;
    const size_t o_tembP= 28875072;
    const size_t o_ub   = 28891456;
    const size_t o_scb  = 28940608;
    const size_t o_mod  = o_traj;
    const size_t o_mod2 = o_traj + 221184;

    const size_t o_wqkv  = 29000000;
    const size_t o_wproj = 34308416;
    const size_t o_wmlp1 = 36077888;
    const size_t o_wmlp2 = 43155776;
    const size_t o_wada  = 50233664;
    const size_t o_wada2 = 60850496;
    const size_t o_wcross= 61440320;
    const size_t o_wmoe1 = 66158912;
    const size_t o_wmoe2 = 94470464;
    const bool bigw = ws_size >= (size_t)123000000 * 4;

    int* cnt_p  = (int*)(ws + o_cnt);
    int* idx_p  = (int*)(ws + o_idx);
    int* list_p = (int*)(ws + o_list);
    float* gval_p = ws + o_gval;
    unsigned short* abf  = (unsigned short*)(ws + o_a);
    unsigned short* bgbf = abf + 512 * 768;
    unsigned short* cgbf = abf + 768 * 768;
    unsigned short* xbf  = (unsigned short*)(ws + o_x);
    unsigned short* lnb  = (unsigned short*)(ws + o_lnb);
    unsigned short* qkvb = (unsigned short*)(ws + o_qkvb);
    unsigned short* attO = (unsigned short*)(ws + o_attnO);
    unsigned short* hbuf = (unsigned short*)(ws + o_h);
    unsigned short* wt   = (unsigned short*)(ws + o_wt);
    unsigned short* wt14 = (unsigned short*)(ws + o_wt14);
    unsigned short* tembP= (unsigned short*)(ws + o_tembP);
    unsigned short* ub   = (unsigned short*)(ws + o_ub);
    unsigned short* scb  = (unsigned short*)(ws + o_scb);
    unsigned short* wqkvS = (unsigned short*)(ws + o_wqkv);
    unsigned short* wprojS= (unsigned short*)(ws + o_wproj);
    unsigned short* wmlp1S= (unsigned short*)(ws + o_wmlp1);
    unsigned short* wmlp2S= (unsigned short*)(ws + o_wmlp2);
    unsigned short* wadaS = (unsigned short*)(ws + o_wada);
    unsigned short* wada2S= (unsigned short*)(ws + o_wada2);
    unsigned short* wcrossS=(unsigned short*)(ws + o_wcross);
    unsigned short* wmoe1S= (unsigned short*)(ws + o_wmoe1);
    unsigned short* wmoe2S= (unsigned short*)(ws + o_wmoe2);
    unsigned short* c_q  = qkvb;
    unsigned short* c_kv = qkvb + 1179648;
    float* scr = ws + o_qkvb;   // split-K scratch (2304*768 f32) — qkvb region, free during MoE

    const size_t WSZ = (size_t)D * D;

    gemm_act<0><<<dim3(12, 32), 256, 0, stream>>>(x_traj, 7, W_traj, D, b_traj,
                                                  ws + o_traj, D, BATCH * TTRAJ, D, 7);
    add_ftime<<<(BATCH * TTRAJ * D + 255) / 256, 256, 0, stream>>>(ws + o_traj, W_ftime, BATCH * TTRAJ * D);

    cvt_bf16<<<(512 * 768 / 8 + 255) / 256, 256, 0, stream>>>(tokA, abf, 512 * 768 / 8);
    cvt_bf16<<<(256 * 768 / 8 + 255) / 256, 256, 0, stream>>>(tokB, bgbf, 256 * 768 / 8);
    cvt_bf16<<<(1536 * 768 / 8 + 255) / 256, 256, 0, stream>>>(tokC, cgbf, 1536 * 768 / 8);
    head_prep<<<42, 256, 0, stream>>>(out_W, wt14);

    if (bigw) {
        tcvt(dit_qkv,  wqkvS,  D, 3 * D, DEPTH, stream);
        tcvt(dit_proj, wprojS, D, D, DEPTH, stream);
        tcvt(dit_mlp1, wmlp1S, D, FF, DEPTH, stream);
        tcvt(dit_mlp2, wmlp2S, FF, D, DEPTH, stream);
        tcvt(dit_ada,  wadaS,  D, 6 * D, DEPTH, stream);
        tcvt(out_adaW, wada2S, D, 2 * D, 1, stream);
        tcvt(moe_attn, wcrossS, D, D, NBLK * 2 * 4, stream);
        tcvt(moe_W1,   wmoe1S, D, FF, NBLK * 3 * NEXP, stream);
        tcvt(moe_W2,   wmoe2S, FF, D, NBLK * 3 * NEXP, stream);
    }

    timestep_kernel<<<128, 256, 0, stream>>>(t_arr, tembP);
    tcvt(Wt1, wt, 256, D, 1, stream);
    gemm_lds<1, 1, 64, 128><<<dim3(12, 1), 256, 0, stream>>>(
        tembP, wt, bt1, nullptr, ub, D, 256, 0, nullptr, 0, 0, 1, 128);
    tcvt(Wt2, wt, D, D, 1, stream);
    gemm_lds<1, 1, 64, 128><<<dim3(12, 1), 256, 0, stream>>>(
        ub, wt, bt2, nullptr, scb, D, D, 0, nullptr, 0, 0, 1, 128);

    for (int i = 0; i < NBLK; ++i) {
        {
            const unsigned short* Wc;
            if (bigw) Wc = wcrossS + (size_t)(i * 2 + 0) * 4 * WSZ;
            else { tcvt(moe_attn + (size_t)(i * 2 + 0) * 4 * WSZ, wt, D, D, 4, stream); Wc = wt; }
            ln_kernel<<<BATCH * NC, 256, 0, stream>>>(cgbf, lnb, BATCH * NC, 1, nullptr, 0, 0, 0);
            g_bf(0, lnb, Wc, nullptr, c_q, D, BATCH * NC, D, D, 768, stream);
            g_bf(0, abf, Wc + 1 * WSZ, nullptr, c_kv, 2 * D, BATCH * NA, 2 * D, D, 0, stream);
            attn_mfma<<<dim3((NC + 127) / 128, NH, BATCH), 512, 0, stream>>>(
                c_q, D, 0, c_kv, 2 * D, 0, c_kv, 2 * D, D, attO, D, NC, NA);
            g_res(attO, Wc + 3 * WSZ, nullptr, cgbf, D, BATCH * NC, D, D, nullptr, 0, 0, 1, stream);
        }
        {
            const unsigned short* Wc;
            if (bigw) Wc = wcrossS + (size_t)(i * 2 + 1) * 4 * WSZ;
            else { tcvt(moe_attn + (size_t)(i * 2 + 1) * 4 * WSZ, wt, D, D, 4, stream); Wc = wt; }
            ln_kernel<<<BATCH * NB, 256, 0, stream>>>(bgbf, lnb, BATCH * NB, 1, nullptr, 0, 0, 0);
            g_bf(0, lnb, Wc, nullptr, c_q, D, BATCH * NB, D, D, 768, stream);
            g_bf(0, cgbf, Wc + 1 * WSZ, nullptr, c_kv, 2 * D, BATCH * NC, 2 * D, D, 0, stream);
            attn_mfma<<<dim3(1, NH, BATCH), 512, 0, stream>>>(
                c_q, D, 0, c_kv, 2 * D, 0, c_kv, 2 * D, D, attO, D, NB, NC);
            g_res(attO, Wc + 3 * WSZ, nullptr, bgbf, D, BATCH * NB, D, D, nullptr, 0, 0, 1, stream);
        }
        ln_kernel<<<MOER, 256, 0, stream>>>(abf, lnb, MOER, 1, nullptr, 0, 0, 0);
        router_kernel<<<MOER, 64, 0, stream>>>(lnb, moe_rout + (size_t)(i * 3) * D * NEXP, idx_p, gval_p);
        scatter_kernel<<<1, 256, 0, stream>>>(idx_p, cnt_p, list_p, MOER);
        const int RT = 12;
        if (bigw) {
            moe_lds<1><<<dim3(24, 12 * RT), 256, 0, stream>>>(
                lnb, wmoe1S + (size_t)(i * 3) * NEXP * D * FF, hbuf,
                cnt_p, list_p, gval_p, RT, 0);
            zero_f32<<<(442368 + 255) / 256, 256, 0, stream>>>(scr, 442368);
            moe_lds2k<<<dim3(12, 12 * RT, 4), 256, 0, stream>>>(
                hbuf, wmoe2S + (size_t)(i * 3) * NEXP * D * FF, scr,
                cnt_p, list_p, RT);
            moe_fin<<<(442368 + 255) / 256, 256, 0, stream>>>(scr, gval_p, abf, 442368);
        } else {
            for (int g = 0; g < 3; ++g) {
                tcvt(moe_W1 + (size_t)(i * 3 + g) * NEXP * D * FF, wt, D, FF, NEXP, stream);
                moe_lds<1><<<dim3(24, 4 * RT), 256, 0, stream>>>(
                    lnb, wt, hbuf, cnt_p, list_p, gval_p, RT, g * 4);
                tcvt(moe_W2 + (size_t)(i * 3 + g) * NEXP * FF * D, wt, FF, D, NEXP, stream);
                moe_lds<2><<<dim3(12, 4 * RT), 256, 0, stream>>>(
                    hbuf, wt, abf, cnt_p, list_p, gval_p, RT, g * 4);
            }
        }
    }

    concat_kernel<<<(BATCH * NTOK * D + 255) / 256, 256, 0, stream>>>(
        ws + o_traj, abf, bgbf, cgbf, xbf, BATCH * NTOK * D);

    if (bigw) {
        gemm_lds<0, 0, 128, 128><<<dim3(36, 1, DEPTH), 256, 0, stream>>>(
            scb, wadaS, dit_adab, ws + o_mod, nullptr, 6 * D, D, 0,
            nullptr, 0, 0, 1, 8,
            (size_t)D * 6 * D, (size_t)6 * D, (size_t)8 * 6 * D);
        gemm_lds<0, 0, 128, 128><<<dim3(12, 1), 256, 0, stream>>>(
            scb, wada2S, out_adab, ws + o_mod2, nullptr, 2 * D, D, 0, nullptr, 0, 0, 1, 8);
    } else {
        for (int i = 0; i < DEPTH; ++i) {
            tcvt(dit_ada + (size_t)i * D * 6 * D, wt, D, 6 * D, 1, stream);
            gemm_lds<0, 0, 128, 128><<<dim3(36, 1), 256, 0, stream>>>(
                scb, wt, dit_adab + (size_t)i * 6 * D, ws + o_mod + (size_t)i * 8 * 6 * D,
                nullptr, 6 * D, D, 0, nullptr, 0, 0, 1, 8);
        }
        tcvt(out_adaW, wt, D, 2 * D, 1, stream);
        gemm_lds<0, 0, 128, 128><<<dim3(12, 1), 256, 0, stream>>>(
            scb, wt, out_adab, ws + o_mod2, nullptr, 2 * D, D, 0, nullptr, 0, 0, 1, 8);
    }

    const int R = BATCH * NTOK;   // 4352 = 17*256
    for (int i = 0; i < DEPTH; ++i) {
        const float* mod_l = ws + o_mod + (size_t)i * 8 * 6 * D;
        const unsigned short *Wq = nullptr, *Wp = nullptr, *Wm1 = nullptr, *Wm2 = nullptr;
        if (bigw) {
            Wq  = wqkvS  + (size_t)i * D * 3 * D;
            Wp  = wprojS + (size_t)i * D * D;
            Wm1 = wmlp1S + (size_t)i * D * FF;
            Wm2 = wmlp2S + (size_t)i * D * FF;
        }
        ln_kernel<<<R, 256, 0, stream>>>(xbf, lnb, R, NTOK, mod_l, 6 * D, 0, 1);
        if (!bigw) { tcvt(dit_qkv + (size_t)i * D * 3 * D, wt, D, 3 * D, 1, stream); Wq = wt; }
        g_bf(0, lnb, Wq, dit_qkvb + (size_t)i * 3 * D, qkvb, 3 * D, R, 3 * D, D, 768, stream);
        attn_mfma<<<dim3((NTOK + 127) / 128, NH, BATCH), 512, 0, stream>>>(
            qkvb, 3 * D, 0, qkvb, 3 * D, D, qkvb, 3 * D, 2 * D, attO, D, NTOK, NTOK);
        if (!bigw) { tcvt(dit_proj + (size_t)i * D * D, wt, D, D, 1, stream); Wp = wt; }
        g_res(attO, Wp, dit_projb + (size_t)i * D, xbf, D, R, D, D,
              mod_l, 6 * D, 2, NTOK, stream);
        ln_kernel<<<R, 256, 0, stream>>>(xbf, lnb, R, NTOK, mod_l, 6 * D, 3, 4);
        if (!bigw) { tcvt(dit_mlp1 + (size_t)i * D * FF, wt, D, FF, 1, stream); Wm1 = wt; }
        g_bf(2, lnb, Wm1, dit_mlp1b + (size_t)i * FF, hbuf, FF, R, FF, D, 0, stream);
        if (!bigw) { tcvt(dit_mlp2 + (size_t)i * FF * D, wt, FF, D, 1, stream); Wm2 = wt; }
        g_res(hbuf, Wm2, dit_mlp2b + (size_t)i * D, xbf, D, R, D, FF,
              mod_l, 6 * D, 5, NTOK, stream);
    }

    ln_kernel<<<R, 256, 0, stream>>>(xbf, lnb, R, NTOK, ws + o_mod2, 2 * D, 0, 1);
    head_kernel<<<BATCH * TTRAJ, 64, 0, stream>>>(lnb, wt14, out_b, out);
}